// Round 3
// baseline (283.327 us; speedup 1.0000x reference)
//
#include <hip/hip_runtime.h>

typedef float        fx4 __attribute__((ext_vector_type(4)));
typedef unsigned int ux4 __attribute__((ext_vector_type(4)));
typedef short        bf8 __attribute__((ext_vector_type(8)));

#define DEVI static __device__ __forceinline__

DEVI unsigned f2bf1(float f) {
  union { float f; unsigned u; } v; v.f = f;
  return (v.u + 0x7FFFu + ((v.u >> 16) & 1u)) >> 16;
}
DEVI float bf2f(unsigned h) {
  union { unsigned u; float f; } v; v.u = h << 16; return v.f;
}
DEVI unsigned cvtpk(float lo, float hi) {
  unsigned r;
  asm("v_cvt_pk_bf16_f32 %0, %1, %2" : "=v"(r) : "v"(lo), "v"(hi));
  return r;
}
DEVI void unp8(ux4 u, float* o) {
  o[0] = bf2f(u[0] & 0xffffu); o[1] = bf2f(u[0] >> 16);
  o[2] = bf2f(u[1] & 0xffffu); o[3] = bf2f(u[1] >> 16);
  o[4] = bf2f(u[2] & 0xffffu); o[5] = bf2f(u[2] >> 16);
  o[6] = bf2f(u[3] & 0xffffu); o[7] = bf2f(u[3] >> 16);
}
DEVI void gload16(const void* g, void* l) {
  __builtin_amdgcn_global_load_lds(
      (const __attribute__((address_space(1))) unsigned*)(uintptr_t)(g),
      (__attribute__((address_space(3))) unsigned*)(unsigned)(uintptr_t)(l),
      16, 0, 0);
}

// ---------------- weight pre-convert: f32 -> bf16 (W1,W2,W3,W4,Wout,cw2 concatenated)
__global__ __launch_bounds__(256) void k_wconv(const float* __restrict__ W1,
                                               const float* __restrict__ W2,
                                               const float* __restrict__ W3,
                                               const float* __restrict__ W4,
                                               const float* __restrict__ Wout,
                                               const float* __restrict__ cw2,
                                               unsigned* __restrict__ dst) {
  const size_t p = (size_t)blockIdx.x * 256 + threadIdx.x;  // pair index
  const float* s; size_t base;
  if (p < 589824)       { s = W1;   base = 0; }
  else if (p < 737280)  { s = W2;   base = 589824; }
  else if (p < 884736)  { s = W3;   base = 737280; }
  else if (p < 1474560) { s = W4;   base = 884736; }
  else if (p < 1548288) { s = Wout; base = 1474560; }
  else if (p < 1552896) { s = cw2;  base = 1548288; }
  else return;
  const size_t lp = p - base;
  dst[p] = cvtpk(s[lp * 2], s[lp * 2 + 1]);
}

// ---------------- transpose + bf16 convert: x (4,1536,576) f32 -> xT (4,576,1536) bf16
__global__ __launch_bounds__(256) void k_transpose(const float* __restrict__ x,
                                                   unsigned short* __restrict__ xT) {
  __shared__ float tile[64][65];
  const int t = threadIdx.x;
  const int b = blockIdx.z, c0 = blockIdx.x * 64, p0 = blockIdx.y * 64;
  const int tl = t & 63, th = t >> 6;
#pragma unroll
  for (int r = 0; r < 16; ++r) {
    int c = th * 16 + r;
    tile[c][tl] = x[((size_t)b * 1536 + c0 + c) * 576 + p0 + tl];
  }
  __syncthreads();
#pragma unroll
  for (int r = 0; r < 16; ++r) {
    int p = th * 16 + r;
    xT[((size_t)b * 576 + p0 + p) * 1536 + c0 + tl] = (unsigned short)f2bf1(tile[tl][p]);
  }
}

// ---------------- bf16 MFMA GEMM, 64(M-rows of A)x128(out-ch) tile, BK=64, dbuf + global_load_lds
// A: bf16 (4,576,K) k-contig; Wb: bf16 (M,K) k-contig; out: bf16 (4,576,M) or FINAL f32 NCHW+resid
template<bool BIASADD, bool FINAL>
__global__ __launch_bounds__(256, 4) void k_gemm(const unsigned short* __restrict__ A,
                                                 const unsigned short* __restrict__ Wb,
                                                 const float* __restrict__ bias,
                                                 const float* __restrict__ resid,
                                                 void* __restrict__ outp, int K, int M) {
  // fragment-ordered LDS: A = 8 subtiles (4 rowgrp x 2 kk) * 64 lanes * 16B
  //                       B = 16 subtiles (8 colgrp x 2 kk) * 64 lanes * 16B
  __shared__ __align__(16) unsigned short As[2][4096];
  __shared__ __align__(16) unsigned short Bs[2][8192];
  const int t = threadIdx.x;
  const int bz = blockIdx.z, j0 = blockIdx.x * 128, i0 = blockIdx.y * 64;
  const int lane = t & 63, wid = t >> 6;
  const int wi = wid >> 1, wj = wid & 1;  // wave tile: 32 rows x 64 cols
  const int lrow = lane & 15, g4 = lane >> 4;

  // staging chunk maps: chunk q -> subtile s=q>>6, lane l=q&63:
  //   row = (q>>7)*16 + (q&15); k = ((q>>6)&1)*32 + ((q>>4)&3)*8
  const int qa0 = t, qa1 = t + 256;
  const int qb0 = t, qb1 = t + 256, qb2 = t + 512, qb3 = t + 768;
#define ROWOF(q) ((((q) >> 7) << 4) + ((q) & 15))
#define KOF(q)   (((((q) >> 6) & 1) << 5) + ((((q) >> 4) & 3) << 3))
  const unsigned short* pa0 = A + ((size_t)(bz * 576 + i0 + ROWOF(qa0))) * K + KOF(qa0);
  const unsigned short* pa1 = A + ((size_t)(bz * 576 + i0 + ROWOF(qa1))) * K + KOF(qa1);
  const unsigned short* pb0 = Wb + ((size_t)(j0 + ROWOF(qb0))) * K + KOF(qb0);
  const unsigned short* pb1 = Wb + ((size_t)(j0 + ROWOF(qb1))) * K + KOF(qb1);
  const unsigned short* pb2 = Wb + ((size_t)(j0 + ROWOF(qb2))) * K + KOF(qb2);
  const unsigned short* pb3 = Wb + ((size_t)(j0 + ROWOF(qb3))) * K + KOF(qb3);
#undef ROWOF
#undef KOF
  auto stage = [&](int buf, int ko) {
    gload16(pa0 + ko, &As[buf][qa0 * 8]);
    gload16(pa1 + ko, &As[buf][qa1 * 8]);
    gload16(pb0 + ko, &Bs[buf][qb0 * 8]);
    gload16(pb1 + ko, &Bs[buf][qb1 * 8]);
    gload16(pb2 + ko, &Bs[buf][qb2 * 8]);
    gload16(pb3 + ko, &Bs[buf][qb3 * 8]);
  };
  fx4 acc[2][4] = {};
  const int nk = K >> 6;
  stage(0, 0);
  __syncthreads();
  int cur = 0;
  for (int ki = 0; ki < nk; ++ki) {
    if (ki + 1 < nk) stage(cur ^ 1, (ki + 1) * 64);
    const unsigned short* ab = &As[cur][0];
    const unsigned short* bb = &Bs[cur][0];
#pragma unroll
    for (int kk = 0; kk < 2; ++kk) {
      bf8 a0 = *(const bf8*)(ab + (((wi * 2 + 0) * 2 + kk) * 64 + lane) * 8);
      bf8 a1 = *(const bf8*)(ab + (((wi * 2 + 1) * 2 + kk) * 64 + lane) * 8);
#pragma unroll
      for (int jt = 0; jt < 4; ++jt) {
        bf8 b = *(const bf8*)(bb + (((wj * 4 + jt) * 2 + kk) * 64 + lane) * 8);
        acc[0][jt] = __builtin_amdgcn_mfma_f32_16x16x32_bf16(a0, b, acc[0][jt], 0, 0, 0);
        acc[1][jt] = __builtin_amdgcn_mfma_f32_16x16x32_bf16(a1, b, acc[1][jt], 0, 0, 0);
      }
    }
    __syncthreads();
    cur ^= 1;
  }
#pragma unroll
  for (int it = 0; it < 2; ++it) {
    const int row0 = i0 + wi * 32 + it * 16 + g4 * 4;
#pragma unroll
    for (int jt = 0; jt < 4; ++jt) {
      fx4 v = acc[it][jt];
      const int m = j0 + wj * 64 + jt * 16 + lrow;
      if (BIASADD) {
        float bv = bias[m];
        v[0] += bv; v[1] += bv; v[2] += bv; v[3] += bv;
      }
      if (FINAL) {
        const fx4 xr = *(const fx4*)(resid + ((size_t)bz * M + m) * 576 + row0);
        fx4 ov;
        ov[0] = fmaxf(v[0] + xr[0], 0.f); ov[1] = fmaxf(v[1] + xr[1], 0.f);
        ov[2] = fmaxf(v[2] + xr[2], 0.f); ov[3] = fmaxf(v[3] + xr[3], 0.f);
        *(fx4*)((float*)outp + ((size_t)bz * M + m) * 576 + row0) = ov;
      } else {
        unsigned short* o = (unsigned short*)outp;
#pragma unroll
        for (int r = 0; r < 4; ++r)
          o[((size_t)(bz * 576) + row0 + r) * M + m] = (unsigned short)f2bf1(fmaxf(v[r], 0.f));
      }
    }
  }
}

// ---------------- grouped 1x1 conv for q
__global__ __launch_bounds__(256) void k_qproj(const unsigned short* __restrict__ h2T,
                                               const float* __restrict__ Wq,
                                               unsigned short* __restrict__ qT) {
  const int idx = blockIdx.x * 256 + threadIdx.x;
  const int c = idx % 384;
  const int n = idx / 384;
  const int g = c / 48, o = c % 48;
  const unsigned short* ap = h2T + (size_t)n * 384 + g * 48;
  const float* wp = Wq + ((size_t)g * 48 + o) * 48;
  float acc = 0.f;
#pragma unroll
  for (int c8 = 0; c8 < 6; ++c8) {
    ux4 u = *(const ux4*)(ap + c8 * 8);
    float va[8]; unp8(u, va);
    fx4 w0 = *(const fx4*)(wp + c8 * 8);
    fx4 w1 = *(const fx4*)(wp + c8 * 8 + 4);
    acc = fmaf(va[0], w0[0], acc); acc = fmaf(va[1], w0[1], acc);
    acc = fmaf(va[2], w0[2], acc); acc = fmaf(va[3], w0[3], acc);
    acc = fmaf(va[4], w1[0], acc); acc = fmaf(va[5], w1[1], acc);
    acc = fmaf(va[6], w1[2], acc); acc = fmaf(va[7], w1[3], acc);
  }
  qT[(size_t)n * 384 + c] = (unsigned short)f2bf1(acc);
}

// ---------------- offsets: depthwise 3x3/s3 -> gelu -> 1x1 (2) -> tanh*4 -> normalized grid
__global__ __launch_bounds__(64, 2) void k_offsets(const unsigned short* __restrict__ qT,
                                                   const float* __restrict__ Wdw,
                                                   const float* __restrict__ bdw,
                                                   const float* __restrict__ Wpw,
                                                   float* __restrict__ vgrid) {
  const int bg = blockIdx.x, t = threadIdx.x;
  const int b = bg >> 3, g = bg & 7;
  const int oy = t >> 3, ox = t & 7;
  float s[48];
#pragma unroll
  for (int ch = 0; ch < 48; ++ch) s[ch] = bdw[ch];
#pragma unroll
  for (int ky = 0; ky < 3; ++ky) {
#pragma unroll
    for (int kx = 0; kx < 3; ++kx) {
      const unsigned short* rp =
          qT + ((size_t)b * 576 + (oy * 3 + ky) * 24 + ox * 3 + kx) * 384 + g * 48;
      const int tap = ky * 3 + kx;
#pragma unroll
      for (int c8 = 0; c8 < 6; ++c8) {
        ux4 u = *(const ux4*)(rp + c8 * 8);
        float va[8]; unp8(u, va);
#pragma unroll
        for (int e = 0; e < 8; ++e)
          s[c8 * 8 + e] = fmaf(va[e], Wdw[(c8 * 8 + e) * 9 + tap], s[c8 * 8 + e]);
      }
    }
  }
  float a0 = 0.f, a1 = 0.f;
#pragma unroll
  for (int ch = 0; ch < 48; ++ch) {
    float z = s[ch];
    float ge = 0.5f * z * (1.f + erff(z * 0.70710678118654752f));
    a0 = fmaf(ge, Wpw[ch], a0);
    a1 = fmaf(ge, Wpw[48 + ch], a1);
  }
  const float off0 = tanhf(a0) * 4.f;
  const float off1 = tanhf(a1) * 4.f;
  vgrid[bg * 128 + t * 2 + 0] = ((float)ox + off0) * (2.f / 7.f) - 1.f;
  vgrid[bg * 128 + t * 2 + 1] = ((float)oy + off1) * (2.f / 7.f) - 1.f;
}

// ---------------- bilinear grid sample (zeros padding, align_corners=False)
__global__ __launch_bounds__(64, 2) void k_gsample(const unsigned short* __restrict__ h2T,
                                                   const float* __restrict__ vgrid,
                                                   unsigned short* __restrict__ kvT) {
  const int bg = blockIdx.x, j = threadIdx.x;
  const int b = bg >> 3, g = bg & 7;
  const float nx = vgrid[bg * 128 + j * 2 + 0];
  const float ny = vgrid[bg * 128 + j * 2 + 1];
  const float xs = ((nx + 1.f) * 24.f - 1.f) * 0.5f;
  const float ys = ((ny + 1.f) * 24.f - 1.f) * 0.5f;
  const float x0f = floorf(xs), y0f = floorf(ys);
  const float wx = xs - x0f, wy = ys - y0f;
  const int x0 = (int)x0f, y0 = (int)y0f;
  float acc[48];
#pragma unroll
  for (int ch = 0; ch < 48; ++ch) acc[ch] = 0.f;
  const float tw[4] = {(1.f - wx) * (1.f - wy), wx * (1.f - wy), (1.f - wx) * wy, wx * wy};
  const int tx[4] = {x0, x0 + 1, x0, x0 + 1};
  const int ty[4] = {y0, y0, y0 + 1, y0 + 1};
#pragma unroll
  for (int tp = 0; tp < 4; ++tp) {
    const int ix = tx[tp], iy = ty[tp];
    const float w = tw[tp] * ((ix >= 0 && ix < 24 && iy >= 0 && iy < 24) ? 1.f : 0.f);
    const int cx = min(max(ix, 0), 23), cy = min(max(iy, 0), 23);
    const unsigned short* rp = h2T + ((size_t)b * 576 + cy * 24 + cx) * 384 + g * 48;
#pragma unroll
    for (int c8 = 0; c8 < 6; ++c8) {
      ux4 u = *(const ux4*)(rp + c8 * 8);
      float va[8]; unp8(u, va);
#pragma unroll
      for (int e = 0; e < 8; ++e) acc[c8 * 8 + e] = fmaf(va[e], w, acc[c8 * 8 + e]);
    }
  }
  unsigned short* op = kvT + ((size_t)bg * 64 + j) * 48;
#pragma unroll
  for (int c2 = 0; c2 < 24; ++c2)
    ((unsigned*)op)[c2] = cvtpk(acc[2 * c2], acc[2 * c2 + 1]);
}

// ---------------- k/v grouped 1x1 conv on kv (f32 out)
__global__ __launch_bounds__(256) void k_kvproj(const unsigned short* __restrict__ kvT,
                                                const float* __restrict__ Wk,
                                                const float* __restrict__ Wv,
                                                float* __restrict__ kT, float* __restrict__ vT) {
  const int bg = blockIdx.x, t = threadIdx.x;
  const int g = bg & 7;
  for (int idx = t; idx < 64 * 48; idx += 256) {
    const int j = idx / 48, o = idx % 48;
    const unsigned short* rp = kvT + ((size_t)bg * 64 + j) * 48;
    const float* wkp = Wk + ((size_t)g * 48 + o) * 48;
    const float* wvp = Wv + ((size_t)g * 48 + o) * 48;
    float ak = 0.f, av = 0.f;
#pragma unroll
    for (int c8 = 0; c8 < 6; ++c8) {
      ux4 u = *(const ux4*)(rp + c8 * 8);
      float va[8]; unp8(u, va);
      fx4 wk0 = *(const fx4*)(wkp + c8 * 8); fx4 wk1 = *(const fx4*)(wkp + c8 * 8 + 4);
      fx4 wv0 = *(const fx4*)(wvp + c8 * 8); fx4 wv1 = *(const fx4*)(wvp + c8 * 8 + 4);
#pragma unroll
      for (int e = 0; e < 4; ++e) {
        ak = fmaf(va[e], wk0[e], ak); ak = fmaf(va[4 + e], wk1[e], ak);
        av = fmaf(va[e], wv0[e], av); av = fmaf(va[4 + e], wv1[e], av);
      }
    }
    kT[(size_t)bg * 3072 + idx] = ak;
    vT[(size_t)bg * 3072 + idx] = av;
  }
}

// ---------------- CPB bias MLP (2 -> 96 -> 96 -> 1): A-frags in registers, cw2 bf16 via gload_lds
// launch_bounds(256,3): VGPR cap ~170 — demand ~110; without this the backend targets 8 waves/EU,
// caps at 48 VGPRs and spills ~64B/thread (79MB of HBM scratch writes, r2 counters).
__global__ __launch_bounds__(256, 3) void k_cpb(const float* __restrict__ vgrid,
                                                const float* __restrict__ cw1,
                                                const float* __restrict__ cb1,
                                                const unsigned short* __restrict__ cw2b,
                                                const float* __restrict__ cb2,
                                                const float* __restrict__ cw3,
                                                const float* __restrict__ cb3,
                                                float* __restrict__ pbias) {
  __shared__ __align__(16) unsigned short Ws[1152 * 8];  // 18 subtiles (6 jt x 3 kk)
  const int t = threadIdx.x;
  const int bg = blockIdx.y;
  const int wid = t >> 6, lane = t & 63;
  const int lrow = lane & 15, g16 = lane >> 4;
  const int i = blockIdx.x * 4 + wid;
  // stage cw2b -> fragment-ordered LDS
#pragma unroll
  for (int rep = 0; rep < 5; ++rep) {
    const int q = t + rep * 256;
    if (q < 1152) {
      const int s = q >> 6, l = q & 63;
      const int jt = s / 3, kk = s - jt * 3;
      const int n = jt * 16 + (l & 15);
      const int k = kk * 32 + ((l >> 4) & 3) * 8;
      gload16(cw2b + (size_t)n * 96 + k, &Ws[q * 8]);
    }
  }
  // layer-1 in registers -> A fragments
  const float qnx = (float)(i % 24) * (2.f / 23.f) - 1.f;
  const float qny = (float)(i / 24) * (2.f / 23.f) - 1.f;
  float uu[4], vv[4];
#pragma unroll
  for (int mt = 0; mt < 4; ++mt) {
    const int j = mt * 16 + lrow;
    const float kx = vgrid[bg * 128 + j * 2 + 0];
    const float ky = vgrid[bg * 128 + j * 2 + 1];
    const float pu = qnx - kx, pv = qny - ky;
    uu[mt] = copysignf(log1pf(fabsf(pu)), pu);
    vv[mt] = copysignf(log1pf(fabsf(pv)), pv);
  }
  bf8 afr[4][3];
#pragma unroll
  for (int kk = 0; kk < 3; ++kk) {
    const int kb = kk * 32 + g16 * 8;
    fx4 w0 = *(const fx4*)(cw1 + kb * 2);
    fx4 w1 = *(const fx4*)(cw1 + kb * 2 + 4);
    fx4 w2 = *(const fx4*)(cw1 + kb * 2 + 8);
    fx4 w3 = *(const fx4*)(cw1 + kb * 2 + 12);
    fx4 b0 = *(const fx4*)(cb1 + kb);
    fx4 b1 = *(const fx4*)(cb1 + kb + 4);
#pragma unroll
    for (int mt = 0; mt < 4; ++mt) {
      float h[8];
      h[0] = fmaxf(fmaf(w0[0], uu[mt], fmaf(w0[1], vv[mt], b0[0])), 0.f);
      h[1] = fmaxf(fmaf(w0[2], uu[mt], fmaf(w0[3], vv[mt], b0[1])), 0.f);
      h[2] = fmaxf(fmaf(w1[0], uu[mt], fmaf(w1[1], vv[mt], b0[2])), 0.f);
      h[3] = fmaxf(fmaf(w1[2], uu[mt], fmaf(w1[3], vv[mt], b0[3])), 0.f);
      h[4] = fmaxf(fmaf(w2[0], uu[mt], fmaf(w2[1], vv[mt], b1[0])), 0.f);
      h[5] = fmaxf(fmaf(w2[2], uu[mt], fmaf(w2[3], vv[mt], b1[1])), 0.f);
      h[6] = fmaxf(fmaf(w3[0], uu[mt], fmaf(w3[1], vv[mt], b1[2])), 0.f);
      h[7] = fmaxf(fmaf(w3[2], uu[mt], fmaf(w3[3], vv[mt], b1[3])), 0.f);
      ux4 pk;
      pk[0] = cvtpk(h[0], h[1]); pk[1] = cvtpk(h[2], h[3]);
      pk[2] = cvtpk(h[4], h[5]); pk[3] = cvtpk(h[6], h[7]);
      afr[mt][kk] = *(bf8*)&pk;
    }
  }
  __syncthreads();
  float part[4][4] = {};
#pragma unroll
  for (int jt = 0; jt < 6; ++jt) {
    bf8 bf0 = *(const bf8*)&Ws[((jt * 3 + 0) * 64 + lane) * 8];
    bf8 bf1 = *(const bf8*)&Ws[((jt * 3 + 1) * 64 + lane) * 8];
    bf8 bf2 = *(const bf8*)&Ws[((jt * 3 + 2) * 64 + lane) * 8];
    const float cb2v = cb2[jt * 16 + lrow];
    const float cw3v = cw3[jt * 16 + lrow];
#pragma unroll
    for (int mt = 0; mt < 4; ++mt) {
      fx4 acc{};
      acc = __builtin_amdgcn_mfma_f32_16x16x32_bf16(afr[mt][0], bf0, acc, 0, 0, 0);
      acc = __builtin_amdgcn_mfma_f32_16x16x32_bf16(afr[mt][1], bf1, acc, 0, 0, 0);
      acc = __builtin_amdgcn_mfma_f32_16x16x32_bf16(afr[mt][2], bf2, acc, 0, 0, 0);
#pragma unroll
      for (int r = 0; r < 4; ++r)
        part[mt][r] = fmaf(fmaxf(acc[r] + cb2v, 0.f), cw3v, part[mt][r]);
    }
  }
  const float cb3v = cb3[0];
#pragma unroll
  for (int mt = 0; mt < 4; ++mt) {
#pragma unroll
    for (int r = 0; r < 4; ++r) {
      part[mt][r] += __shfl_xor(part[mt][r], 1);
      part[mt][r] += __shfl_xor(part[mt][r], 2);
      part[mt][r] += __shfl_xor(part[mt][r], 4);
      part[mt][r] += __shfl_xor(part[mt][r], 8);
    }
    float pv2 = part[mt][0];
    pv2 = (lrow == 1) ? part[mt][1] : pv2;
    pv2 = (lrow == 2) ? part[mt][2] : pv2;
    pv2 = (lrow == 3) ? part[mt][3] : pv2;
    if (lrow < 4) {
      const int j = mt * 16 + g16 * 4 + lrow;
      pbias[((size_t)bg * 576 + i) * 64 + j] = pv2 + cb3v;
    }
  }
}

// ---------------- attention: 4 lanes per query, 16 keys each; shfl-reduce softmax & PV
__global__ __launch_bounds__(256, 3) void k_attn(const unsigned short* __restrict__ qT,
                                                 const float* __restrict__ kT,
                                                 const float* __restrict__ vT,
                                                 const float* __restrict__ pbias,
                                                 unsigned short* __restrict__ aoT) {
  __shared__ __align__(16) float kls[3072];
  __shared__ __align__(16) float vls[3072];
  const int t = threadIdx.x;
  const int ic = blockIdx.x, h = blockIdx.y, b = blockIdx.z;
  const int bg = b * 8 + h;
#pragma unroll
  for (int r = 0; r < 3; ++r) {
    const int idx = t + r * 256;
    ((fx4*)kls)[idx] = ((const fx4*)(kT + (size_t)bg * 3072))[idx];
    ((fx4*)vls)[idx] = ((const fx4*)(vT + (size_t)bg * 3072))[idx];
  }
  __syncthreads();
  const int qi = ic * 64 + (t >> 2);
  const int kg = t & 3;
  const unsigned short* qp = qT + ((size_t)b * 576 + qi) * 384 + h * 48;
  const float scale = 0.14433756729740643f;  // 48^-0.5
  float q[48];
#pragma unroll
  for (int c8 = 0; c8 < 6; ++c8) {
    ux4 u = *(const ux4*)(qp + c8 * 8);
    float va[8]; unp8(u, va);
#pragma unroll
    for (int e = 0; e < 8; ++e) q[c8 * 8 + e] = va[e] * scale;
  }
  float s[16];
  const float* kbase = kls + kg * 16 * 48;
#pragma unroll
  for (int it = 0; it < 16; ++it) {
    const fx4* kr = (const fx4*)(kbase + it * 48);
    float a0 = 0.f, a1 = 0.f;
#pragma unroll
    for (int d4 = 0; d4 < 6; ++d4) {
      fx4 k0 = kr[2 * d4], k1 = kr[2 * d4 + 1];
      a0 = fmaf(q[8 * d4 + 0], k0[0], a0); a0 = fmaf(q[8 * d4 + 1], k0[1], a0);
      a0 = fmaf(q[8 * d4 + 2], k0[2], a0); a0 = fmaf(q[8 * d4 + 3], k0[3], a0);
      a1 = fmaf(q[8 * d4 + 4], k1[0], a1); a1 = fmaf(q[8 * d4 + 5], k1[1], a1);
      a1 = fmaf(q[8 * d4 + 6], k1[2], a1); a1 = fmaf(q[8 * d4 + 7], k1[3], a1);
    }
    s[it] = a0 + a1;
  }
  const float* bp = pbias + ((size_t)bg * 576 + qi) * 64 + kg * 16;
#pragma unroll
  for (int i4 = 0; i4 < 4; ++i4) {
    fx4 bv = ((const fx4*)bp)[i4];
    s[i4 * 4 + 0] += bv[0]; s[i4 * 4 + 1] += bv[1];
    s[i4 * 4 + 2] += bv[2]; s[i4 * 4 + 3] += bv[3];
  }
  float mx = s[0];
#pragma unroll
  for (int it = 1; it < 16; ++it) mx = fmaxf(mx, s[it]);
  mx = fmaxf(mx, __shfl_xor(mx, 1));
  mx = fmaxf(mx, __shfl_xor(mx, 2));
  float sum = 0.f;
#pragma unroll
  for (int it = 0; it < 16; ++it) { s[it] = __expf(s[it] - mx); sum += s[it]; }
  sum += __shfl_xor(sum, 1);
  sum += __shfl_xor(sum, 2);
  const float inv = 1.f / sum;
#pragma unroll
  for (int it = 0; it < 16; ++it) s[it] *= inv;
  float acc[48];
#pragma unroll
  for (int d = 0; d < 48; ++d) acc[d] = 0.f;
  const float* vbase = vls + kg * 16 * 48;
#pragma unroll
  for (int it = 0; it < 16; ++it) {
    const float p = s[it];
    const fx4* vr = (const fx4*)(vbase + it * 48);
#pragma unroll
    for (int d4 = 0; d4 < 12; ++d4) {
      fx4 v = vr[d4];
      acc[d4 * 4 + 0] = fmaf(p, v[0], acc[d4 * 4 + 0]);
      acc[d4 * 4 + 1] = fmaf(p, v[1], acc[d4 * 4 + 1]);
      acc[d4 * 4 + 2] = fmaf(p, v[2], acc[d4 * 4 + 2]);
      acc[d4 * 4 + 3] = fmaf(p, v[3], acc[d4 * 4 + 3]);
    }
  }
#pragma unroll
  for (int d = 0; d < 48; ++d) {
    acc[d] += __shfl_xor(acc[d], 1);
    acc[d] += __shfl_xor(acc[d], 2);
  }
  unsigned* op32 = (unsigned*)(aoT + ((size_t)b * 576 + qi) * 384 + h * 48);
  if (kg == 0) {
#pragma unroll
    for (int p2 = 0; p2 < 6; ++p2) op32[p2] = cvtpk(acc[p2 * 2], acc[p2 * 2 + 1]);
  } else if (kg == 1) {
#pragma unroll
    for (int p2 = 0; p2 < 6; ++p2) op32[6 + p2] = cvtpk(acc[12 + p2 * 2], acc[13 + p2 * 2]);
  } else if (kg == 2) {
#pragma unroll
    for (int p2 = 0; p2 < 6; ++p2) op32[12 + p2] = cvtpk(acc[24 + p2 * 2], acc[25 + p2 * 2]);
  } else {
#pragma unroll
    for (int p2 = 0; p2 < 6; ++p2) op32[18 + p2] = cvtpk(acc[36 + p2 * 2], acc[37 + p2 * 2]);
  }
}

extern "C" void kernel_launch(void* const* d_in, const int* in_sizes, int n_in,
                              void* d_out, int out_size, void* d_ws, size_t ws_size,
                              hipStream_t stream) {
  (void)in_sizes; (void)n_in; (void)out_size; (void)ws_size;
  const float* x    = (const float*)d_in[0];
  const float* W1   = (const float*)d_in[1];
  const float* W2   = (const float*)d_in[2];
  const float* W3   = (const float*)d_in[3];
  const float* W4   = (const float*)d_in[4];
  const float* Wq   = (const float*)d_in[5];
  const float* Wk   = (const float*)d_in[6];
  const float* Wv   = (const float*)d_in[7];
  const float* Wdw  = (const float*)d_in[8];
  const float* bdw  = (const float*)d_in[9];
  const float* Wpw  = (const float*)d_in[10];
  const float* cw1  = (const float*)d_in[11];
  const float* cb1  = (const float*)d_in[12];
  const float* cw2  = (const float*)d_in[13];
  const float* cb2  = (const float*)d_in[14];
  const float* cw3  = (const float*)d_in[15];
  const float* cb3  = (const float*)d_in[16];
  const float* Wout = (const float*)d_in[17];
  const float* bout = (const float*)d_in[18];

  char* ws = (char*)d_ws;
  size_t off = 0;
  auto alloc = [&](size_t bytes) {
    void* p = ws + off;
    off += (bytes + 255) & ~(size_t)255;
    return p;
  };
  unsigned short* xT  = (unsigned short*)alloc((size_t)4 * 576 * 1536 * 2);
  unsigned short* h1T = (unsigned short*)alloc((size_t)4 * 576 * 768 * 2);
  unsigned short* h2T = (unsigned short*)alloc((size_t)4 * 576 * 384 * 2);
  unsigned short* qT  = (unsigned short*)alloc((size_t)4 * 576 * 384 * 2);
  unsigned short* aoT = (unsigned short*)alloc((size_t)4 * 576 * 384 * 2);
  unsigned short* AT  = (unsigned short*)alloc((size_t)4 * 576 * 384 * 2);
  unsigned short* h3T = (unsigned short*)alloc((size_t)4 * 576 * 768 * 2);
  float* vgrid = (float*)alloc((size_t)32 * 64 * 2 * 4);
  unsigned short* kvT = (unsigned short*)alloc((size_t)32 * 64 * 48 * 2);
  float* kTb  = (float*)alloc((size_t)32 * 64 * 48 * 4);
  float* vTb  = (float*)alloc((size_t)32 * 64 * 48 * 4);
  float* pbias = (float*)alloc((size_t)32 * 576 * 64 * 4);
  unsigned short* Wcvt = (unsigned short*)alloc((size_t)3105792 * 2);  // bf16 weights
  const unsigned short* W1b   = Wcvt;
  const unsigned short* W2b   = Wcvt + 1179648;
  const unsigned short* W3b   = Wcvt + 1474560;
  const unsigned short* W4b   = Wcvt + 1769472;
  const unsigned short* Woutb = Wcvt + 2949120;
  const unsigned short* cw2b  = Wcvt + 3096576;

  k_wconv<<<6066, 256, 0, stream>>>(W1, W2, W3, W4, Wout, cw2, (unsigned*)Wcvt);
  k_transpose<<<dim3(24, 9, 4), 256, 0, stream>>>(x, xT);
  k_gemm<false, false><<<dim3(6, 9, 4), 256, 0, stream>>>(xT, W1b, nullptr, nullptr, h1T, 1536, 768);
  k_gemm<false, false><<<dim3(3, 9, 4), 256, 0, stream>>>(h1T, W2b, nullptr, nullptr, h2T, 768, 384);
  k_qproj<<<3456, 256, 0, stream>>>(h2T, Wq, qT);
  k_offsets<<<32, 64, 0, stream>>>(qT, Wdw, bdw, Wpw, vgrid);
  k_gsample<<<32, 64, 0, stream>>>(h2T, vgrid, kvT);
  k_kvproj<<<32, 256, 0, stream>>>(kvT, Wk, Wv, kTb, vTb);
  k_cpb<<<dim3(144, 32), 256, 0, stream>>>(vgrid, cw1, cb1, cw2b, cb2, cw3, cb3, pbias);
  k_attn<<<dim3(9, 8, 4), 256, 0, stream>>>(qT, kTb, vTb, pbias, aoT);
  k_gemm<true, false><<<dim3(3, 9, 4), 256, 0, stream>>>(aoT, Woutb, bout, nullptr, AT, 384, 384);
  k_gemm<false, false><<<dim3(6, 9, 4), 256, 0, stream>>>(AT, W3b, nullptr, nullptr, h3T, 384, 768);
  k_gemm<false, true><<<dim3(12, 9, 4), 256, 0, stream>>>(h3T, W4b, nullptr, x, d_out, 768, 1536);
}

// Round 4
// 260.982 us; speedup vs baseline: 1.0856x; 1.0856x over previous
//
#include <hip/hip_runtime.h>

typedef float        fx4 __attribute__((ext_vector_type(4)));
typedef unsigned int ux4 __attribute__((ext_vector_type(4)));
typedef short        bf8 __attribute__((ext_vector_type(8)));

#define DEVI static __device__ __forceinline__

DEVI unsigned f2bf1(float f) {
  union { float f; unsigned u; } v; v.f = f;
  return (v.u + 0x7FFFu + ((v.u >> 16) & 1u)) >> 16;
}
DEVI float bf2f(unsigned h) {
  union { unsigned u; float f; } v; v.u = h << 16; return v.f;
}
DEVI unsigned cvtpk(float lo, float hi) {
  unsigned r;
  asm("v_cvt_pk_bf16_f32 %0, %1, %2" : "=v"(r) : "v"(lo), "v"(hi));
  return r;
}
DEVI void unp8(ux4 u, float* o) {
  o[0] = bf2f(u[0] & 0xffffu); o[1] = bf2f(u[0] >> 16);
  o[2] = bf2f(u[1] & 0xffffu); o[3] = bf2f(u[1] >> 16);
  o[4] = bf2f(u[2] & 0xffffu); o[5] = bf2f(u[2] >> 16);
  o[6] = bf2f(u[3] & 0xffffu); o[7] = bf2f(u[3] >> 16);
}
DEVI void gload16(const void* g, void* l) {
  __builtin_amdgcn_global_load_lds(
      (const __attribute__((address_space(1))) unsigned*)(uintptr_t)(g),
      (__attribute__((address_space(3))) unsigned*)(unsigned)(uintptr_t)(l),
      16, 0, 0);
}

// ---------------- weight pre-convert: f32 -> bf16 (W1,W2,W3,W4,Wout,cw2 concatenated)
__global__ __launch_bounds__(256) void k_wconv(const float* __restrict__ W1,
                                               const float* __restrict__ W2,
                                               const float* __restrict__ W3,
                                               const float* __restrict__ W4,
                                               const float* __restrict__ Wout,
                                               const float* __restrict__ cw2,
                                               unsigned* __restrict__ dst) {
  const size_t p = (size_t)blockIdx.x * 256 + threadIdx.x;  // pair index
  const float* s; size_t base;
  if (p < 589824)       { s = W1;   base = 0; }
  else if (p < 737280)  { s = W2;   base = 589824; }
  else if (p < 884736)  { s = W3;   base = 737280; }
  else if (p < 1474560) { s = W4;   base = 884736; }
  else if (p < 1548288) { s = Wout; base = 1474560; }
  else if (p < 1552896) { s = cw2;  base = 1548288; }
  else return;
  const size_t lp = p - base;
  dst[p] = cvtpk(s[lp * 2], s[lp * 2 + 1]);
}

// ---------------- transpose + bf16 convert: x (4,1536,576) f32 -> xT (4,576,1536) bf16
__global__ __launch_bounds__(256) void k_transpose(const float* __restrict__ x,
                                                   unsigned short* __restrict__ xT) {
  __shared__ float tile[64][65];
  const int t = threadIdx.x;
  const int b = blockIdx.z, c0 = blockIdx.x * 64, p0 = blockIdx.y * 64;
  const int tl = t & 63, th = t >> 6;
#pragma unroll
  for (int r = 0; r < 16; ++r) {
    int c = th * 16 + r;
    tile[c][tl] = x[((size_t)b * 1536 + c0 + c) * 576 + p0 + tl];
  }
  __syncthreads();
#pragma unroll
  for (int r = 0; r < 16; ++r) {
    int p = th * 16 + r;
    xT[((size_t)b * 576 + p0 + p) * 1536 + c0 + tl] = (unsigned short)f2bf1(tile[tl][p]);
  }
}

// ---------------- bf16 MFMA GEMM, 64(M-rows of A)x128(out-ch) tile, BK=64, dbuf + global_load_lds
// A: bf16 (4,576,K) k-contig; Wb: bf16 (M,K) k-contig; out: bf16 (4,576,M) or FINAL f32 NCHW+resid
template<bool BIASADD, bool FINAL>
__global__ __launch_bounds__(256, 4) void k_gemm(const unsigned short* __restrict__ A,
                                                 const unsigned short* __restrict__ Wb,
                                                 const float* __restrict__ bias,
                                                 const float* __restrict__ resid,
                                                 void* __restrict__ outp, int K, int M) {
  // fragment-ordered LDS: A = 8 subtiles (4 rowgrp x 2 kk) * 64 lanes * 16B
  //                       B = 16 subtiles (8 colgrp x 2 kk) * 64 lanes * 16B
  __shared__ __align__(16) unsigned short As[2][4096];
  __shared__ __align__(16) unsigned short Bs[2][8192];
  const int t = threadIdx.x;
  const int bz = blockIdx.z, j0 = blockIdx.x * 128, i0 = blockIdx.y * 64;
  const int lane = t & 63, wid = t >> 6;
  const int wi = wid >> 1, wj = wid & 1;  // wave tile: 32 rows x 64 cols
  const int lrow = lane & 15, g4 = lane >> 4;

  // staging chunk maps: chunk q -> subtile s=q>>6, lane l=q&63:
  //   row = (q>>7)*16 + (q&15); k = ((q>>6)&1)*32 + ((q>>4)&3)*8
  const int qa0 = t, qa1 = t + 256;
  const int qb0 = t, qb1 = t + 256, qb2 = t + 512, qb3 = t + 768;
#define ROWOF(q) ((((q) >> 7) << 4) + ((q) & 15))
#define KOF(q)   (((((q) >> 6) & 1) << 5) + ((((q) >> 4) & 3) << 3))
  const unsigned short* pa0 = A + ((size_t)(bz * 576 + i0 + ROWOF(qa0))) * K + KOF(qa0);
  const unsigned short* pa1 = A + ((size_t)(bz * 576 + i0 + ROWOF(qa1))) * K + KOF(qa1);
  const unsigned short* pb0 = Wb + ((size_t)(j0 + ROWOF(qb0))) * K + KOF(qb0);
  const unsigned short* pb1 = Wb + ((size_t)(j0 + ROWOF(qb1))) * K + KOF(qb1);
  const unsigned short* pb2 = Wb + ((size_t)(j0 + ROWOF(qb2))) * K + KOF(qb2);
  const unsigned short* pb3 = Wb + ((size_t)(j0 + ROWOF(qb3))) * K + KOF(qb3);
#undef ROWOF
#undef KOF
  auto stage = [&](int buf, int ko) {
    gload16(pa0 + ko, &As[buf][qa0 * 8]);
    gload16(pa1 + ko, &As[buf][qa1 * 8]);
    gload16(pb0 + ko, &Bs[buf][qb0 * 8]);
    gload16(pb1 + ko, &Bs[buf][qb1 * 8]);
    gload16(pb2 + ko, &Bs[buf][qb2 * 8]);
    gload16(pb3 + ko, &Bs[buf][qb3 * 8]);
  };
  fx4 acc[2][4] = {};
  const int nk = K >> 6;
  stage(0, 0);
  __syncthreads();
  int cur = 0;
  for (int ki = 0; ki < nk; ++ki) {
    if (ki + 1 < nk) stage(cur ^ 1, (ki + 1) * 64);
    const unsigned short* ab = &As[cur][0];
    const unsigned short* bb = &Bs[cur][0];
#pragma unroll
    for (int kk = 0; kk < 2; ++kk) {
      bf8 a0 = *(const bf8*)(ab + (((wi * 2 + 0) * 2 + kk) * 64 + lane) * 8);
      bf8 a1 = *(const bf8*)(ab + (((wi * 2 + 1) * 2 + kk) * 64 + lane) * 8);
#pragma unroll
      for (int jt = 0; jt < 4; ++jt) {
        bf8 b = *(const bf8*)(bb + (((wj * 4 + jt) * 2 + kk) * 64 + lane) * 8);
        acc[0][jt] = __builtin_amdgcn_mfma_f32_16x16x32_bf16(a0, b, acc[0][jt], 0, 0, 0);
        acc[1][jt] = __builtin_amdgcn_mfma_f32_16x16x32_bf16(a1, b, acc[1][jt], 0, 0, 0);
      }
    }
    __syncthreads();
    cur ^= 1;
  }
#pragma unroll
  for (int it = 0; it < 2; ++it) {
    const int row0 = i0 + wi * 32 + it * 16 + g4 * 4;
#pragma unroll
    for (int jt = 0; jt < 4; ++jt) {
      fx4 v = acc[it][jt];
      const int m = j0 + wj * 64 + jt * 16 + lrow;
      if (BIASADD) {
        float bv = bias[m];
        v[0] += bv; v[1] += bv; v[2] += bv; v[3] += bv;
      }
      if (FINAL) {
        const fx4 xr = *(const fx4*)(resid + ((size_t)bz * M + m) * 576 + row0);
        fx4 ov;
        ov[0] = fmaxf(v[0] + xr[0], 0.f); ov[1] = fmaxf(v[1] + xr[1], 0.f);
        ov[2] = fmaxf(v[2] + xr[2], 0.f); ov[3] = fmaxf(v[3] + xr[3], 0.f);
        *(fx4*)((float*)outp + ((size_t)bz * M + m) * 576 + row0) = ov;
      } else {
        unsigned short* o = (unsigned short*)outp;
#pragma unroll
        for (int r = 0; r < 4; ++r)
          o[((size_t)(bz * 576) + row0 + r) * M + m] = (unsigned short)f2bf1(fmaxf(v[r], 0.f));
      }
    }
  }
}

// ---------------- grouped 1x1 conv for q
__global__ __launch_bounds__(256) void k_qproj(const unsigned short* __restrict__ h2T,
                                               const float* __restrict__ Wq,
                                               unsigned short* __restrict__ qT) {
  const int idx = blockIdx.x * 256 + threadIdx.x;
  const int c = idx % 384;
  const int n = idx / 384;
  const int g = c / 48, o = c % 48;
  const unsigned short* ap = h2T + (size_t)n * 384 + g * 48;
  const float* wp = Wq + ((size_t)g * 48 + o) * 48;
  float acc = 0.f;
#pragma unroll
  for (int c8 = 0; c8 < 6; ++c8) {
    ux4 u = *(const ux4*)(ap + c8 * 8);
    float va[8]; unp8(u, va);
    fx4 w0 = *(const fx4*)(wp + c8 * 8);
    fx4 w1 = *(const fx4*)(wp + c8 * 8 + 4);
    acc = fmaf(va[0], w0[0], acc); acc = fmaf(va[1], w0[1], acc);
    acc = fmaf(va[2], w0[2], acc); acc = fmaf(va[3], w0[3], acc);
    acc = fmaf(va[4], w1[0], acc); acc = fmaf(va[5], w1[1], acc);
    acc = fmaf(va[6], w1[2], acc); acc = fmaf(va[7], w1[3], acc);
  }
  qT[(size_t)n * 384 + c] = (unsigned short)f2bf1(acc);
}

// ---------------- offsets: depthwise 3x3/s3 -> gelu -> 1x1 (2) -> tanh*4 -> normalized grid
__global__ __launch_bounds__(64, 2) void k_offsets(const unsigned short* __restrict__ qT,
                                                   const float* __restrict__ Wdw,
                                                   const float* __restrict__ bdw,
                                                   const float* __restrict__ Wpw,
                                                   float* __restrict__ vgrid) {
  const int bg = blockIdx.x, t = threadIdx.x;
  const int b = bg >> 3, g = bg & 7;
  const int oy = t >> 3, ox = t & 7;
  float s[48];
#pragma unroll
  for (int ch = 0; ch < 48; ++ch) s[ch] = bdw[ch];
#pragma unroll
  for (int ky = 0; ky < 3; ++ky) {
#pragma unroll
    for (int kx = 0; kx < 3; ++kx) {
      const unsigned short* rp =
          qT + ((size_t)b * 576 + (oy * 3 + ky) * 24 + ox * 3 + kx) * 384 + g * 48;
      const int tap = ky * 3 + kx;
#pragma unroll
      for (int c8 = 0; c8 < 6; ++c8) {
        ux4 u = *(const ux4*)(rp + c8 * 8);
        float va[8]; unp8(u, va);
#pragma unroll
        for (int e = 0; e < 8; ++e)
          s[c8 * 8 + e] = fmaf(va[e], Wdw[(c8 * 8 + e) * 9 + tap], s[c8 * 8 + e]);
      }
    }
  }
  float a0 = 0.f, a1 = 0.f;
#pragma unroll
  for (int ch = 0; ch < 48; ++ch) {
    float z = s[ch];
    float ge = 0.5f * z * (1.f + erff(z * 0.70710678118654752f));
    a0 = fmaf(ge, Wpw[ch], a0);
    a1 = fmaf(ge, Wpw[48 + ch], a1);
  }
  const float off0 = tanhf(a0) * 4.f;
  const float off1 = tanhf(a1) * 4.f;
  vgrid[bg * 128 + t * 2 + 0] = ((float)ox + off0) * (2.f / 7.f) - 1.f;
  vgrid[bg * 128 + t * 2 + 1] = ((float)oy + off1) * (2.f / 7.f) - 1.f;
}

// ---------------- bilinear grid sample (zeros padding, align_corners=False)
__global__ __launch_bounds__(64, 2) void k_gsample(const unsigned short* __restrict__ h2T,
                                                   const float* __restrict__ vgrid,
                                                   unsigned short* __restrict__ kvT) {
  const int bg = blockIdx.x, j = threadIdx.x;
  const int b = bg >> 3, g = bg & 7;
  const float nx = vgrid[bg * 128 + j * 2 + 0];
  const float ny = vgrid[bg * 128 + j * 2 + 1];
  const float xs = ((nx + 1.f) * 24.f - 1.f) * 0.5f;
  const float ys = ((ny + 1.f) * 24.f - 1.f) * 0.5f;
  const float x0f = floorf(xs), y0f = floorf(ys);
  const float wx = xs - x0f, wy = ys - y0f;
  const int x0 = (int)x0f, y0 = (int)y0f;
  float acc[48];
#pragma unroll
  for (int ch = 0; ch < 48; ++ch) acc[ch] = 0.f;
  const float tw[4] = {(1.f - wx) * (1.f - wy), wx * (1.f - wy), (1.f - wx) * wy, wx * wy};
  const int tx[4] = {x0, x0 + 1, x0, x0 + 1};
  const int ty[4] = {y0, y0, y0 + 1, y0 + 1};
#pragma unroll
  for (int tp = 0; tp < 4; ++tp) {
    const int ix = tx[tp], iy = ty[tp];
    const float w = tw[tp] * ((ix >= 0 && ix < 24 && iy >= 0 && iy < 24) ? 1.f : 0.f);
    const int cx = min(max(ix, 0), 23), cy = min(max(iy, 0), 23);
    const unsigned short* rp = h2T + ((size_t)b * 576 + cy * 24 + cx) * 384 + g * 48;
#pragma unroll
    for (int c8 = 0; c8 < 6; ++c8) {
      ux4 u = *(const ux4*)(rp + c8 * 8);
      float va[8]; unp8(u, va);
#pragma unroll
      for (int e = 0; e < 8; ++e) acc[c8 * 8 + e] = fmaf(va[e], w, acc[c8 * 8 + e]);
    }
  }
  unsigned short* op = kvT + ((size_t)bg * 64 + j) * 48;
#pragma unroll
  for (int c2 = 0; c2 < 24; ++c2)
    ((unsigned*)op)[c2] = cvtpk(acc[2 * c2], acc[2 * c2 + 1]);
}

// ---------------- k/v grouped 1x1 conv on kv (f32 out)
__global__ __launch_bounds__(256) void k_kvproj(const unsigned short* __restrict__ kvT,
                                                const float* __restrict__ Wk,
                                                const float* __restrict__ Wv,
                                                float* __restrict__ kT, float* __restrict__ vT) {
  const int bg = blockIdx.x, t = threadIdx.x;
  const int g = bg & 7;
  for (int idx = t; idx < 64 * 48; idx += 256) {
    const int j = idx / 48, o = idx % 48;
    const unsigned short* rp = kvT + ((size_t)bg * 64 + j) * 48;
    const float* wkp = Wk + ((size_t)g * 48 + o) * 48;
    const float* wvp = Wv + ((size_t)g * 48 + o) * 48;
    float ak = 0.f, av = 0.f;
#pragma unroll
    for (int c8 = 0; c8 < 6; ++c8) {
      ux4 u = *(const ux4*)(rp + c8 * 8);
      float va[8]; unp8(u, va);
      fx4 wk0 = *(const fx4*)(wkp + c8 * 8); fx4 wk1 = *(const fx4*)(wkp + c8 * 8 + 4);
      fx4 wv0 = *(const fx4*)(wvp + c8 * 8); fx4 wv1 = *(const fx4*)(wvp + c8 * 8 + 4);
#pragma unroll
      for (int e = 0; e < 4; ++e) {
        ak = fmaf(va[e], wk0[e], ak); ak = fmaf(va[4 + e], wk1[e], ak);
        av = fmaf(va[e], wv0[e], av); av = fmaf(va[4 + e], wv1[e], av);
      }
    }
    kT[(size_t)bg * 3072 + idx] = ak;
    vT[(size_t)bg * 3072 + idx] = av;
  }
}

// ---------------- CPB bias MLP (2 -> 96 -> 96 -> 1): A-frags + B-frags in registers
// launch_bounds(256,2): 256-VGPR cap. Live demand ~150 (afr 48 + bfr 72 + part 16 + temps).
// r2/r3 post-mortem: tighter caps (48/68 VGPRs) spilled afr to scratch; 6 jt iterations
// re-loaded it -> 112us latency-bound, MfmaUtil 8%. __logf replaces libm log1pf.
__global__ __launch_bounds__(256, 2) void k_cpb(const float* __restrict__ vgrid,
                                                const float* __restrict__ cw1,
                                                const float* __restrict__ cb1,
                                                const unsigned short* __restrict__ cw2b,
                                                const float* __restrict__ cb2,
                                                const float* __restrict__ cw3,
                                                const float* __restrict__ cb3,
                                                float* __restrict__ pbias) {
  __shared__ __align__(16) unsigned short Ws[1152 * 8];  // 18 subtiles (6 jt x 3 kk)
  const int t = threadIdx.x;
  const int bg = blockIdx.y;
  const int wid = t >> 6, lane = t & 63;
  const int lrow = lane & 15, g16 = lane >> 4;
  const int i = blockIdx.x * 4 + wid;
  // stage cw2b -> fragment-ordered LDS
#pragma unroll
  for (int rep = 0; rep < 5; ++rep) {
    const int q = t + rep * 256;
    if (q < 1152) {
      const int s = q >> 6, l = q & 63;
      const int jt = s / 3, kk = s - jt * 3;
      const int n = jt * 16 + (l & 15);
      const int k = kk * 32 + ((l >> 4) & 3) * 8;
      gload16(cw2b + (size_t)n * 96 + k, &Ws[q * 8]);
    }
  }
  // layer-1 in registers -> A fragments
  const float qnx = (float)(i % 24) * (2.f / 23.f) - 1.f;
  const float qny = (float)(i / 24) * (2.f / 23.f) - 1.f;
  float uu[4], vv[4];
#pragma unroll
  for (int mt = 0; mt < 4; ++mt) {
    const int j = mt * 16 + lrow;
    const float kx = vgrid[bg * 128 + j * 2 + 0];
    const float ky = vgrid[bg * 128 + j * 2 + 1];
    const float pu = qnx - kx, pv = qny - ky;
    uu[mt] = copysignf(__logf(1.f + fabsf(pu)), pu);
    vv[mt] = copysignf(__logf(1.f + fabsf(pv)), pv);
  }
  bf8 afr[4][3];
#pragma unroll
  for (int kk = 0; kk < 3; ++kk) {
    const int kb = kk * 32 + g16 * 8;
    fx4 w0 = *(const fx4*)(cw1 + kb * 2);
    fx4 w1 = *(const fx4*)(cw1 + kb * 2 + 4);
    fx4 w2 = *(const fx4*)(cw1 + kb * 2 + 8);
    fx4 w3 = *(const fx4*)(cw1 + kb * 2 + 12);
    fx4 b0 = *(const fx4*)(cb1 + kb);
    fx4 b1 = *(const fx4*)(cb1 + kb + 4);
#pragma unroll
    for (int mt = 0; mt < 4; ++mt) {
      float h[8];
      h[0] = fmaxf(fmaf(w0[0], uu[mt], fmaf(w0[1], vv[mt], b0[0])), 0.f);
      h[1] = fmaxf(fmaf(w0[2], uu[mt], fmaf(w0[3], vv[mt], b0[1])), 0.f);
      h[2] = fmaxf(fmaf(w1[0], uu[mt], fmaf(w1[1], vv[mt], b0[2])), 0.f);
      h[3] = fmaxf(fmaf(w1[2], uu[mt], fmaf(w1[3], vv[mt], b0[3])), 0.f);
      h[4] = fmaxf(fmaf(w2[0], uu[mt], fmaf(w2[1], vv[mt], b1[0])), 0.f);
      h[5] = fmaxf(fmaf(w2[2], uu[mt], fmaf(w2[3], vv[mt], b1[1])), 0.f);
      h[6] = fmaxf(fmaf(w3[0], uu[mt], fmaf(w3[1], vv[mt], b1[2])), 0.f);
      h[7] = fmaxf(fmaf(w3[2], uu[mt], fmaf(w3[3], vv[mt], b1[3])), 0.f);
      ux4 pk;
      pk[0] = cvtpk(h[0], h[1]); pk[1] = cvtpk(h[2], h[3]);
      pk[2] = cvtpk(h[4], h[5]); pk[3] = cvtpk(h[6], h[7]);
      afr[mt][kk] = *(bf8*)&pk;
    }
  }
  __syncthreads();
  // hoist all B fragments to registers (block-uniform cw2 tiles; 72 VGPRs)
  bf8 bfr[6][3];
#pragma unroll
  for (int jt = 0; jt < 6; ++jt)
#pragma unroll
    for (int kk = 0; kk < 3; ++kk)
      bfr[jt][kk] = *(const bf8*)&Ws[((jt * 3 + kk) * 64 + lane) * 8];
  float part[4][4] = {};
#pragma unroll
  for (int jt = 0; jt < 6; ++jt) {
    const float cb2v = cb2[jt * 16 + lrow];
    const float cw3v = cw3[jt * 16 + lrow];
#pragma unroll
    for (int mt = 0; mt < 4; ++mt) {
      fx4 acc{};
      acc = __builtin_amdgcn_mfma_f32_16x16x32_bf16(afr[mt][0], bfr[jt][0], acc, 0, 0, 0);
      acc = __builtin_amdgcn_mfma_f32_16x16x32_bf16(afr[mt][1], bfr[jt][1], acc, 0, 0, 0);
      acc = __builtin_amdgcn_mfma_f32_16x16x32_bf16(afr[mt][2], bfr[jt][2], acc, 0, 0, 0);
#pragma unroll
      for (int r = 0; r < 4; ++r)
        part[mt][r] = fmaf(fmaxf(acc[r] + cb2v, 0.f), cw3v, part[mt][r]);
    }
  }
  const float cb3v = cb3[0];
#pragma unroll
  for (int mt = 0; mt < 4; ++mt) {
#pragma unroll
    for (int r = 0; r < 4; ++r) {
      part[mt][r] += __shfl_xor(part[mt][r], 1);
      part[mt][r] += __shfl_xor(part[mt][r], 2);
      part[mt][r] += __shfl_xor(part[mt][r], 4);
      part[mt][r] += __shfl_xor(part[mt][r], 8);
    }
    float pv2 = part[mt][0];
    pv2 = (lrow == 1) ? part[mt][1] : pv2;
    pv2 = (lrow == 2) ? part[mt][2] : pv2;
    pv2 = (lrow == 3) ? part[mt][3] : pv2;
    if (lrow < 4) {
      const int j = mt * 16 + g16 * 4 + lrow;
      pbias[((size_t)bg * 576 + i) * 64 + j] = pv2 + cb3v;
    }
  }
}

// ---------------- attention: 4 lanes per query, 16 keys each; shfl-reduce softmax & PV
__global__ __launch_bounds__(256, 3) void k_attn(const unsigned short* __restrict__ qT,
                                                 const float* __restrict__ kT,
                                                 const float* __restrict__ vT,
                                                 const float* __restrict__ pbias,
                                                 unsigned short* __restrict__ aoT) {
  __shared__ __align__(16) float kls[3072];
  __shared__ __align__(16) float vls[3072];
  const int t = threadIdx.x;
  const int ic = blockIdx.x, h = blockIdx.y, b = blockIdx.z;
  const int bg = b * 8 + h;
#pragma unroll
  for (int r = 0; r < 3; ++r) {
    const int idx = t + r * 256;
    ((fx4*)kls)[idx] = ((const fx4*)(kT + (size_t)bg * 3072))[idx];
    ((fx4*)vls)[idx] = ((const fx4*)(vT + (size_t)bg * 3072))[idx];
  }
  __syncthreads();
  const int qi = ic * 64 + (t >> 2);
  const int kg = t & 3;
  const unsigned short* qp = qT + ((size_t)b * 576 + qi) * 384 + h * 48;
  const float scale = 0.14433756729740643f;  // 48^-0.5
  float q[48];
#pragma unroll
  for (int c8 = 0; c8 < 6; ++c8) {
    ux4 u = *(const ux4*)(qp + c8 * 8);
    float va[8]; unp8(u, va);
#pragma unroll
    for (int e = 0; e < 8; ++e) q[c8 * 8 + e] = va[e] * scale;
  }
  float s[16];
  const float* kbase = kls + kg * 16 * 48;
#pragma unroll
  for (int it = 0; it < 16; ++it) {
    const fx4* kr = (const fx4*)(kbase + it * 48);
    float a0 = 0.f, a1 = 0.f;
#pragma unroll
    for (int d4 = 0; d4 < 6; ++d4) {
      fx4 k0 = kr[2 * d4], k1 = kr[2 * d4 + 1];
      a0 = fmaf(q[8 * d4 + 0], k0[0], a0); a0 = fmaf(q[8 * d4 + 1], k0[1], a0);
      a0 = fmaf(q[8 * d4 + 2], k0[2], a0); a0 = fmaf(q[8 * d4 + 3], k0[3], a0);
      a1 = fmaf(q[8 * d4 + 4], k1[0], a1); a1 = fmaf(q[8 * d4 + 5], k1[1], a1);
      a1 = fmaf(q[8 * d4 + 6], k1[2], a1); a1 = fmaf(q[8 * d4 + 7], k1[3], a1);
    }
    s[it] = a0 + a1;
  }
  const float* bp = pbias + ((size_t)bg * 576 + qi) * 64 + kg * 16;
#pragma unroll
  for (int i4 = 0; i4 < 4; ++i4) {
    fx4 bv = ((const fx4*)bp)[i4];
    s[i4 * 4 + 0] += bv[0]; s[i4 * 4 + 1] += bv[1];
    s[i4 * 4 + 2] += bv[2]; s[i4 * 4 + 3] += bv[3];
  }
  float mx = s[0];
#pragma unroll
  for (int it = 1; it < 16; ++it) mx = fmaxf(mx, s[it]);
  mx = fmaxf(mx, __shfl_xor(mx, 1));
  mx = fmaxf(mx, __shfl_xor(mx, 2));
  float sum = 0.f;
#pragma unroll
  for (int it = 0; it < 16; ++it) { s[it] = __expf(s[it] - mx); sum += s[it]; }
  sum += __shfl_xor(sum, 1);
  sum += __shfl_xor(sum, 2);
  const float inv = 1.f / sum;
#pragma unroll
  for (int it = 0; it < 16; ++it) s[it] *= inv;
  float acc[48];
#pragma unroll
  for (int d = 0; d < 48; ++d) acc[d] = 0.f;
  const float* vbase = vls + kg * 16 * 48;
#pragma unroll
  for (int it = 0; it < 16; ++it) {
    const float p = s[it];
    const fx4* vr = (const fx4*)(vbase + it * 48);
#pragma unroll
    for (int d4 = 0; d4 < 12; ++d4) {
      fx4 v = vr[d4];
      acc[d4 * 4 + 0] = fmaf(p, v[0], acc[d4 * 4 + 0]);
      acc[d4 * 4 + 1] = fmaf(p, v[1], acc[d4 * 4 + 1]);
      acc[d4 * 4 + 2] = fmaf(p, v[2], acc[d4 * 4 + 2]);
      acc[d4 * 4 + 3] = fmaf(p, v[3], acc[d4 * 4 + 3]);
    }
  }
#pragma unroll
  for (int d = 0; d < 48; ++d) {
    acc[d] += __shfl_xor(acc[d], 1);
    acc[d] += __shfl_xor(acc[d], 2);
  }
  unsigned* op32 = (unsigned*)(aoT + ((size_t)b * 576 + qi) * 384 + h * 48);
  if (kg == 0) {
#pragma unroll
    for (int p2 = 0; p2 < 6; ++p2) op32[p2] = cvtpk(acc[p2 * 2], acc[p2 * 2 + 1]);
  } else if (kg == 1) {
#pragma unroll
    for (int p2 = 0; p2 < 6; ++p2) op32[6 + p2] = cvtpk(acc[12 + p2 * 2], acc[13 + p2 * 2]);
  } else if (kg == 2) {
#pragma unroll
    for (int p2 = 0; p2 < 6; ++p2) op32[12 + p2] = cvtpk(acc[24 + p2 * 2], acc[25 + p2 * 2]);
  } else {
#pragma unroll
    for (int p2 = 0; p2 < 6; ++p2) op32[18 + p2] = cvtpk(acc[36 + p2 * 2], acc[37 + p2 * 2]);
  }
}

extern "C" void kernel_launch(void* const* d_in, const int* in_sizes, int n_in,
                              void* d_out, int out_size, void* d_ws, size_t ws_size,
                              hipStream_t stream) {
  (void)in_sizes; (void)n_in; (void)out_size; (void)ws_size;
  const float* x    = (const float*)d_in[0];
  const float* W1   = (const float*)d_in[1];
  const float* W2   = (const float*)d_in[2];
  const float* W3   = (const float*)d_in[3];
  const float* W4   = (const float*)d_in[4];
  const float* Wq   = (const float*)d_in[5];
  const float* Wk   = (const float*)d_in[6];
  const float* Wv   = (const float*)d_in[7];
  const float* Wdw  = (const float*)d_in[8];
  const float* bdw  = (const float*)d_in[9];
  const float* Wpw  = (const float*)d_in[10];
  const float* cw1  = (const float*)d_in[11];
  const float* cb1  = (const float*)d_in[12];
  const float* cw2  = (const float*)d_in[13];
  const float* cb2  = (const float*)d_in[14];
  const float* cw3  = (const float*)d_in[15];
  const float* cb3  = (const float*)d_in[16];
  const float* Wout = (const float*)d_in[17];
  const float* bout = (const float*)d_in[18];

  char* ws = (char*)d_ws;
  size_t off = 0;
  auto alloc = [&](size_t bytes) {
    void* p = ws + off;
    off += (bytes + 255) & ~(size_t)255;
    return p;
  };
  unsigned short* xT  = (unsigned short*)alloc((size_t)4 * 576 * 1536 * 2);
  unsigned short* h1T = (unsigned short*)alloc((size_t)4 * 576 * 768 * 2);
  unsigned short* h2T = (unsigned short*)alloc((size_t)4 * 576 * 384 * 2);
  unsigned short* qT  = (unsigned short*)alloc((size_t)4 * 576 * 384 * 2);
  unsigned short* aoT = (unsigned short*)alloc((size_t)4 * 576 * 384 * 2);
  unsigned short* AT  = (unsigned short*)alloc((size_t)4 * 576 * 384 * 2);
  unsigned short* h3T = (unsigned short*)alloc((size_t)4 * 576 * 768 * 2);
  float* vgrid = (float*)alloc((size_t)32 * 64 * 2 * 4);
  unsigned short* kvT = (unsigned short*)alloc((size_t)32 * 64 * 48 * 2);
  float* kTb  = (float*)alloc((size_t)32 * 64 * 48 * 4);
  float* vTb  = (float*)alloc((size_t)32 * 64 * 48 * 4);
  float* pbias = (float*)alloc((size_t)32 * 576 * 64 * 4);
  unsigned short* Wcvt = (unsigned short*)alloc((size_t)3105792 * 2);  // bf16 weights
  const unsigned short* W1b   = Wcvt;
  const unsigned short* W2b   = Wcvt + 1179648;
  const unsigned short* W3b   = Wcvt + 1474560;
  const unsigned short* W4b   = Wcvt + 1769472;
  const unsigned short* Woutb = Wcvt + 2949120;
  const unsigned short* cw2b  = Wcvt + 3096576;

  k_wconv<<<6066, 256, 0, stream>>>(W1, W2, W3, W4, Wout, cw2, (unsigned*)Wcvt);
  k_transpose<<<dim3(24, 9, 4), 256, 0, stream>>>(x, xT);
  k_gemm<false, false><<<dim3(6, 9, 4), 256, 0, stream>>>(xT, W1b, nullptr, nullptr, h1T, 1536, 768);
  k_gemm<false, false><<<dim3(3, 9, 4), 256, 0, stream>>>(h1T, W2b, nullptr, nullptr, h2T, 768, 384);
  k_qproj<<<3456, 256, 0, stream>>>(h2T, Wq, qT);
  k_offsets<<<32, 64, 0, stream>>>(qT, Wdw, bdw, Wpw, vgrid);
  k_gsample<<<32, 64, 0, stream>>>(h2T, vgrid, kvT);
  k_kvproj<<<32, 256, 0, stream>>>(kvT, Wk, Wv, kTb, vTb);
  k_cpb<<<dim3(144, 32), 256, 0, stream>>>(vgrid, cw1, cb1, cw2b, cb2, cw3, cb3, pbias);
  k_attn<<<dim3(9, 8, 4), 256, 0, stream>>>(qT, kTb, vTb, pbias, aoT);
  k_gemm<true, false><<<dim3(3, 9, 4), 256, 0, stream>>>(aoT, Woutb, bout, nullptr, AT, 384, 384);
  k_gemm<false, false><<<dim3(6, 9, 4), 256, 0, stream>>>(AT, W3b, nullptr, nullptr, h3T, 384, 768);
  k_gemm<false, true><<<dim3(12, 9, 4), 256, 0, stream>>>(h3T, W4b, nullptr, x, d_out, 768, 1536);
}

// Round 5
// 229.234 us; speedup vs baseline: 1.2360x; 1.1385x over previous
//
#include <hip/hip_runtime.h>

typedef float        fx4 __attribute__((ext_vector_type(4)));
typedef unsigned int ux4 __attribute__((ext_vector_type(4)));
typedef short        bf8 __attribute__((ext_vector_type(8)));

#define DEVI static __device__ __forceinline__

DEVI unsigned f2bf1(float f) {
  union { float f; unsigned u; } v; v.f = f;
  return (v.u + 0x7FFFu + ((v.u >> 16) & 1u)) >> 16;
}
DEVI float bf2f(unsigned h) {
  union { unsigned u; float f; } v; v.u = h << 16; return v.f;
}
DEVI unsigned cvtpk(float lo, float hi) {
  unsigned r;
  asm("v_cvt_pk_bf16_f32 %0, %1, %2" : "=v"(r) : "v"(lo), "v"(hi));
  return r;
}
DEVI void unp8(ux4 u, float* o) {
  o[0] = bf2f(u[0] & 0xffffu); o[1] = bf2f(u[0] >> 16);
  o[2] = bf2f(u[1] & 0xffffu); o[3] = bf2f(u[1] >> 16);
  o[4] = bf2f(u[2] & 0xffffu); o[5] = bf2f(u[2] >> 16);
  o[6] = bf2f(u[3] & 0xffffu); o[7] = bf2f(u[3] >> 16);
}
DEVI void gload16(const void* g, void* l) {
  __builtin_amdgcn_global_load_lds(
      (const __attribute__((address_space(1))) unsigned*)(uintptr_t)(g),
      (__attribute__((address_space(3))) unsigned*)(unsigned)(uintptr_t)(l),
      16, 0, 0);
}

// ---------------- weight pre-convert: f32 -> bf16 (W1,W2,W3,W4,Wout,cw2 concatenated)
__global__ __launch_bounds__(256) void k_wconv(const float* __restrict__ W1,
                                               const float* __restrict__ W2,
                                               const float* __restrict__ W3,
                                               const float* __restrict__ W4,
                                               const float* __restrict__ Wout,
                                               const float* __restrict__ cw2,
                                               unsigned* __restrict__ dst) {
  const size_t p = (size_t)blockIdx.x * 256 + threadIdx.x;  // pair index
  const float* s; size_t base;
  if (p < 589824)       { s = W1;   base = 0; }
  else if (p < 737280)  { s = W2;   base = 589824; }
  else if (p < 884736)  { s = W3;   base = 737280; }
  else if (p < 1474560) { s = W4;   base = 884736; }
  else if (p < 1548288) { s = Wout; base = 1474560; }
  else if (p < 1552896) { s = cw2;  base = 1548288; }
  else return;
  const size_t lp = p - base;
  dst[p] = cvtpk(s[lp * 2], s[lp * 2 + 1]);
}

// ---------------- transpose + bf16 convert: x (4,1536,576) f32 -> xT (4,576,1536) bf16
__global__ __launch_bounds__(256) void k_transpose(const float* __restrict__ x,
                                                   unsigned short* __restrict__ xT) {
  __shared__ float tile[64][65];
  const int t = threadIdx.x;
  const int b = blockIdx.z, c0 = blockIdx.x * 64, p0 = blockIdx.y * 64;
  const int tl = t & 63, th = t >> 6;
#pragma unroll
  for (int r = 0; r < 16; ++r) {
    int c = th * 16 + r;
    tile[c][tl] = x[((size_t)b * 1536 + c0 + c) * 576 + p0 + tl];
  }
  __syncthreads();
#pragma unroll
  for (int r = 0; r < 16; ++r) {
    int p = th * 16 + r;
    xT[((size_t)b * 576 + p0 + p) * 1536 + c0 + tl] = (unsigned short)f2bf1(tile[tl][p]);
  }
}

// ---------------- bf16 MFMA GEMM, 64 x BN tile, BK=64, 3-deep pipeline w/ counted vmcnt
// A: bf16 (4,576,K) k-contig; Wb: bf16 (M,K) k-contig; out: bf16 (4,576,M) or FINAL f32 NCHW+resid
// chunk q -> row = (q>>7)*16 + (q&15); k = ((q>>6)&1)*32 + ((q>>4)&3)*8   (fragment-ordered LDS)
#define ROWOF(q) ((((q) >> 7) << 4) + ((q) & 15))
#define KOF(q)   (((((q) >> 6) & 1) << 5) + ((((q) >> 4) & 3) << 3))
template<int BN, bool BIASADD, bool FINAL>
__global__ __launch_bounds__(256, 4) void k_gemm(const unsigned short* __restrict__ A,
                                                 const unsigned short* __restrict__ Wb,
                                                 const float* __restrict__ bias,
                                                 const float* __restrict__ resid,
                                                 void* __restrict__ outp, int K, int M) {
  constexpr int BCH = BN / 32;  // B staging chunks per thread (2|4); A is always 2
  constexpr int NJT = BN / 32;  // 16-col fragments per wave (wave tile 32 x BN/2)
  __shared__ __align__(16) unsigned short As[3][4096];
  __shared__ __align__(16) unsigned short Bs[3][BN * 64];
  const int t = threadIdx.x;
  const int bz = blockIdx.z, j0 = blockIdx.x * BN, i0 = blockIdx.y * 64;
  const int lane = t & 63, wid = t >> 6;
  const int wi = wid >> 1, wj = wid & 1;
  const int lrow = lane & 15, g4 = lane >> 4;

  const unsigned short* pa0 = A + ((size_t)(bz * 576 + i0 + ROWOF(t))) * K + KOF(t);
  const unsigned short* pa1 = A + ((size_t)(bz * 576 + i0 + ROWOF(t + 256))) * K + KOF(t + 256);
  const unsigned short* pb[BCH];
#pragma unroll
  for (int c = 0; c < BCH; ++c) {
    const int q = t + c * 256;
    pb[c] = Wb + ((size_t)(j0 + ROWOF(q))) * K + KOF(q);
  }
  auto stage = [&](int buf, int ko) {
    gload16(pa0 + ko, &As[buf][t * 8]);
    gload16(pa1 + ko, &As[buf][(t + 256) * 8]);
#pragma unroll
    for (int c = 0; c < BCH; ++c) gload16(pb[c] + ko, &Bs[buf][(t + c * 256) * 8]);
  };
  fx4 acc[2][NJT] = {};
  const int nk = K >> 6;
  stage(0, 0);
  if (nk > 1) stage(1, 64);
  int cur = 0;
  for (int ki = 0; ki < nk; ++ki) {
    // wait: oldest stage (buf=cur) landed; keep next stage(s) in flight across the barrier
    if (ki + 1 < nk) {
      if constexpr (BCH == 2) asm volatile("s_waitcnt vmcnt(4)" ::: "memory");
      else                    asm volatile("s_waitcnt vmcnt(6)" ::: "memory");
    } else {
      asm volatile("s_waitcnt vmcnt(0)" ::: "memory");
    }
    __builtin_amdgcn_s_barrier();
    __builtin_amdgcn_sched_barrier(0);
    asm volatile("" ::: "memory");
    if (ki + 2 < nk) {
      int b2 = cur - 1; if (b2 < 0) b2 = 2;  // (cur+2)%3: the buffer consumed in iter ki-1
      stage(b2, (ki + 2) * 64);
    }
    const unsigned short* ab = &As[cur][0];
    const unsigned short* bb = &Bs[cur][0];
#pragma unroll
    for (int kk = 0; kk < 2; ++kk) {
      bf8 a0 = *(const bf8*)(ab + (((wi * 2 + 0) * 2 + kk) * 64 + lane) * 8);
      bf8 a1 = *(const bf8*)(ab + (((wi * 2 + 1) * 2 + kk) * 64 + lane) * 8);
#pragma unroll
      for (int jt = 0; jt < NJT; ++jt) {
        bf8 b = *(const bf8*)(bb + (((wj * NJT + jt) * 2 + kk) * 64 + lane) * 8);
        acc[0][jt] = __builtin_amdgcn_mfma_f32_16x16x32_bf16(a0, b, acc[0][jt], 0, 0, 0);
        acc[1][jt] = __builtin_amdgcn_mfma_f32_16x16x32_bf16(a1, b, acc[1][jt], 0, 0, 0);
      }
    }
    cur = (cur == 2) ? 0 : cur + 1;
  }
#pragma unroll
  for (int it = 0; it < 2; ++it) {
    const int row0 = i0 + wi * 32 + it * 16 + g4 * 4;
#pragma unroll
    for (int jt = 0; jt < NJT; ++jt) {
      fx4 v = acc[it][jt];
      const int m = j0 + wj * (BN / 2) + jt * 16 + lrow;
      if (BIASADD) {
        float bv = bias[m];
        v[0] += bv; v[1] += bv; v[2] += bv; v[3] += bv;
      }
      if (FINAL) {
        const fx4 xr = *(const fx4*)(resid + ((size_t)bz * M + m) * 576 + row0);
        fx4 ov;
        ov[0] = fmaxf(v[0] + xr[0], 0.f); ov[1] = fmaxf(v[1] + xr[1], 0.f);
        ov[2] = fmaxf(v[2] + xr[2], 0.f); ov[3] = fmaxf(v[3] + xr[3], 0.f);
        *(fx4*)((float*)outp + ((size_t)bz * M + m) * 576 + row0) = ov;
      } else {
        unsigned short* o = (unsigned short*)outp;
#pragma unroll
        for (int r = 0; r < 4; ++r)
          o[((size_t)(bz * 576) + row0 + r) * M + m] = (unsigned short)f2bf1(fmaxf(v[r], 0.f));
      }
    }
  }
}
#undef ROWOF
#undef KOF

// ---------------- grouped 1x1 conv for q
__global__ __launch_bounds__(256) void k_qproj(const unsigned short* __restrict__ h2T,
                                               const float* __restrict__ Wq,
                                               unsigned short* __restrict__ qT) {
  const int idx = blockIdx.x * 256 + threadIdx.x;
  const int c = idx % 384;
  const int n = idx / 384;
  const int g = c / 48, o = c % 48;
  const unsigned short* ap = h2T + (size_t)n * 384 + g * 48;
  const float* wp = Wq + ((size_t)g * 48 + o) * 48;
  float acc = 0.f;
#pragma unroll
  for (int c8 = 0; c8 < 6; ++c8) {
    ux4 u = *(const ux4*)(ap + c8 * 8);
    float va[8]; unp8(u, va);
    fx4 w0 = *(const fx4*)(wp + c8 * 8);
    fx4 w1 = *(const fx4*)(wp + c8 * 8 + 4);
    acc = fmaf(va[0], w0[0], acc); acc = fmaf(va[1], w0[1], acc);
    acc = fmaf(va[2], w0[2], acc); acc = fmaf(va[3], w0[3], acc);
    acc = fmaf(va[4], w1[0], acc); acc = fmaf(va[5], w1[1], acc);
    acc = fmaf(va[6], w1[2], acc); acc = fmaf(va[7], w1[3], acc);
  }
  qT[(size_t)n * 384 + c] = (unsigned short)f2bf1(acc);
}

// ---------------- offsets: depthwise 3x3/s3 -> gelu -> 1x1 (2) -> tanh*4 -> normalized grid
__global__ __launch_bounds__(64, 2) void k_offsets(const unsigned short* __restrict__ qT,
                                                   const float* __restrict__ Wdw,
                                                   const float* __restrict__ bdw,
                                                   const float* __restrict__ Wpw,
                                                   float* __restrict__ vgrid) {
  const int bg = blockIdx.x, t = threadIdx.x;
  const int b = bg >> 3, g = bg & 7;
  const int oy = t >> 3, ox = t & 7;
  float s[48];
#pragma unroll
  for (int ch = 0; ch < 48; ++ch) s[ch] = bdw[ch];
#pragma unroll
  for (int ky = 0; ky < 3; ++ky) {
#pragma unroll
    for (int kx = 0; kx < 3; ++kx) {
      const unsigned short* rp =
          qT + ((size_t)b * 576 + (oy * 3 + ky) * 24 + ox * 3 + kx) * 384 + g * 48;
      const int tap = ky * 3 + kx;
#pragma unroll
      for (int c8 = 0; c8 < 6; ++c8) {
        ux4 u = *(const ux4*)(rp + c8 * 8);
        float va[8]; unp8(u, va);
#pragma unroll
        for (int e = 0; e < 8; ++e)
          s[c8 * 8 + e] = fmaf(va[e], Wdw[(c8 * 8 + e) * 9 + tap], s[c8 * 8 + e]);
      }
    }
  }
  float a0 = 0.f, a1 = 0.f;
#pragma unroll
  for (int ch = 0; ch < 48; ++ch) {
    float z = s[ch];
    float ge = 0.5f * z * (1.f + erff(z * 0.70710678118654752f));
    a0 = fmaf(ge, Wpw[ch], a0);
    a1 = fmaf(ge, Wpw[48 + ch], a1);
  }
  const float off0 = tanhf(a0) * 4.f;
  const float off1 = tanhf(a1) * 4.f;
  vgrid[bg * 128 + t * 2 + 0] = ((float)ox + off0) * (2.f / 7.f) - 1.f;
  vgrid[bg * 128 + t * 2 + 1] = ((float)oy + off1) * (2.f / 7.f) - 1.f;
}

// ---------------- bilinear grid sample (zeros padding, align_corners=False)
__global__ __launch_bounds__(64, 2) void k_gsample(const unsigned short* __restrict__ h2T,
                                                   const float* __restrict__ vgrid,
                                                   unsigned short* __restrict__ kvT) {
  const int bg = blockIdx.x, j = threadIdx.x;
  const int b = bg >> 3, g = bg & 7;
  const float nx = vgrid[bg * 128 + j * 2 + 0];
  const float ny = vgrid[bg * 128 + j * 2 + 1];
  const float xs = ((nx + 1.f) * 24.f - 1.f) * 0.5f;
  const float ys = ((ny + 1.f) * 24.f - 1.f) * 0.5f;
  const float x0f = floorf(xs), y0f = floorf(ys);
  const float wx = xs - x0f, wy = ys - y0f;
  const int x0 = (int)x0f, y0 = (int)y0f;
  float acc[48];
#pragma unroll
  for (int ch = 0; ch < 48; ++ch) acc[ch] = 0.f;
  const float tw[4] = {(1.f - wx) * (1.f - wy), wx * (1.f - wy), (1.f - wx) * wy, wx * wy};
  const int tx[4] = {x0, x0 + 1, x0, x0 + 1};
  const int ty[4] = {y0, y0, y0 + 1, y0 + 1};
#pragma unroll
  for (int tp = 0; tp < 4; ++tp) {
    const int ix = tx[tp], iy = ty[tp];
    const float w = tw[tp] * ((ix >= 0 && ix < 24 && iy >= 0 && iy < 24) ? 1.f : 0.f);
    const int cx = min(max(ix, 0), 23), cy = min(max(iy, 0), 23);
    const unsigned short* rp = h2T + ((size_t)b * 576 + cy * 24 + cx) * 384 + g * 48;
#pragma unroll
    for (int c8 = 0; c8 < 6; ++c8) {
      ux4 u = *(const ux4*)(rp + c8 * 8);
      float va[8]; unp8(u, va);
#pragma unroll
      for (int e = 0; e < 8; ++e) acc[c8 * 8 + e] = fmaf(va[e], w, acc[c8 * 8 + e]);
    }
  }
  unsigned short* op = kvT + ((size_t)bg * 64 + j) * 48;
#pragma unroll
  for (int c2 = 0; c2 < 24; ++c2)
    ((unsigned*)op)[c2] = cvtpk(acc[2 * c2], acc[2 * c2 + 1]);
}

// ---------------- k/v grouped 1x1 conv on kv (f32 out)
__global__ __launch_bounds__(256) void k_kvproj(const unsigned short* __restrict__ kvT,
                                                const float* __restrict__ Wk,
                                                const float* __restrict__ Wv,
                                                float* __restrict__ kT, float* __restrict__ vT) {
  const int bg = blockIdx.x, t = threadIdx.x;
  const int g = bg & 7;
  for (int idx = t; idx < 64 * 48; idx += 256) {
    const int j = idx / 48, o = idx % 48;
    const unsigned short* rp = kvT + ((size_t)bg * 64 + j) * 48;
    const float* wkp = Wk + ((size_t)g * 48 + o) * 48;
    const float* wvp = Wv + ((size_t)g * 48 + o) * 48;
    float ak = 0.f, av = 0.f;
#pragma unroll
    for (int c8 = 0; c8 < 6; ++c8) {
      ux4 u = *(const ux4*)(rp + c8 * 8);
      float va[8]; unp8(u, va);
      fx4 wk0 = *(const fx4*)(wkp + c8 * 8); fx4 wk1 = *(const fx4*)(wkp + c8 * 8 + 4);
      fx4 wv0 = *(const fx4*)(wvp + c8 * 8); fx4 wv1 = *(const fx4*)(wvp + c8 * 8 + 4);
#pragma unroll
      for (int e = 0; e < 4; ++e) {
        ak = fmaf(va[e], wk0[e], ak); ak = fmaf(va[4 + e], wk1[e], ak);
        av = fmaf(va[e], wv0[e], av); av = fmaf(va[4 + e], wv1[e], av);
      }
    }
    kT[(size_t)bg * 3072 + idx] = ak;
    vT[(size_t)bg * 3072 + idx] = av;
  }
}

// ---------------- CPB bias MLP (2 -> 96 -> 96 -> 1): A-frags + B-frags in registers
// amdgpu_waves_per_eu(2,2): pin the allocator's occupancy TARGET to 2 waves/EU (budget 256
// VGPRs). r2-r4 post-mortems: launch_bounds only CAPS the budget; the allocator still
// targeted LDS-derived 8 waves/EU and allocated 48-72 regs vs ~150 live demand -> per-thread
// scratch spill/reload chains dominated (89-112us, MfmaUtil 8-10%).
__global__ __launch_bounds__(256)
__attribute__((amdgpu_waves_per_eu(2, 2))) void k_cpb(const float* __restrict__ vgrid,
                                                const float* __restrict__ cw1,
                                                const float* __restrict__ cb1,
                                                const unsigned short* __restrict__ cw2b,
                                                const float* __restrict__ cb2,
                                                const float* __restrict__ cw3,
                                                const float* __restrict__ cb3,
                                                float* __restrict__ pbias) {
  __shared__ __align__(16) unsigned short Ws[1152 * 8];  // 18 subtiles (6 jt x 3 kk)
  const int t = threadIdx.x;
  const int bg = blockIdx.y;
  const int wid = t >> 6, lane = t & 63;
  const int lrow = lane & 15, g16 = lane >> 4;
  const int i = blockIdx.x * 4 + wid;
  // stage cw2b -> fragment-ordered LDS
#pragma unroll
  for (int rep = 0; rep < 5; ++rep) {
    const int q = t + rep * 256;
    if (q < 1152) {
      const int s = q >> 6, l = q & 63;
      const int jt = s / 3, kk = s - jt * 3;
      const int n = jt * 16 + (l & 15);
      const int k = kk * 32 + ((l >> 4) & 3) * 8;
      gload16(cw2b + (size_t)n * 96 + k, &Ws[q * 8]);
    }
  }
  // layer-1 in registers -> A fragments
  const float qnx = (float)(i % 24) * (2.f / 23.f) - 1.f;
  const float qny = (float)(i / 24) * (2.f / 23.f) - 1.f;
  float uu[4], vv[4];
#pragma unroll
  for (int mt = 0; mt < 4; ++mt) {
    const int j = mt * 16 + lrow;
    const float kx = vgrid[bg * 128 + j * 2 + 0];
    const float ky = vgrid[bg * 128 + j * 2 + 1];
    const float pu = qnx - kx, pv = qny - ky;
    uu[mt] = copysignf(__logf(1.f + fabsf(pu)), pu);
    vv[mt] = copysignf(__logf(1.f + fabsf(pv)), pv);
  }
  bf8 afr[4][3];
#pragma unroll
  for (int kk = 0; kk < 3; ++kk) {
    const int kb = kk * 32 + g16 * 8;
    fx4 w0 = *(const fx4*)(cw1 + kb * 2);
    fx4 w1 = *(const fx4*)(cw1 + kb * 2 + 4);
    fx4 w2 = *(const fx4*)(cw1 + kb * 2 + 8);
    fx4 w3 = *(const fx4*)(cw1 + kb * 2 + 12);
    fx4 b0 = *(const fx4*)(cb1 + kb);
    fx4 b1 = *(const fx4*)(cb1 + kb + 4);
#pragma unroll
    for (int mt = 0; mt < 4; ++mt) {
      float h[8];
      h[0] = fmaxf(fmaf(w0[0], uu[mt], fmaf(w0[1], vv[mt], b0[0])), 0.f);
      h[1] = fmaxf(fmaf(w0[2], uu[mt], fmaf(w0[3], vv[mt], b0[1])), 0.f);
      h[2] = fmaxf(fmaf(w1[0], uu[mt], fmaf(w1[1], vv[mt], b0[2])), 0.f);
      h[3] = fmaxf(fmaf(w1[2], uu[mt], fmaf(w1[3], vv[mt], b0[3])), 0.f);
      h[4] = fmaxf(fmaf(w2[0], uu[mt], fmaf(w2[1], vv[mt], b1[0])), 0.f);
      h[5] = fmaxf(fmaf(w2[2], uu[mt], fmaf(w2[3], vv[mt], b1[1])), 0.f);
      h[6] = fmaxf(fmaf(w3[0], uu[mt], fmaf(w3[1], vv[mt], b1[2])), 0.f);
      h[7] = fmaxf(fmaf(w3[2], uu[mt], fmaf(w3[3], vv[mt], b1[3])), 0.f);
      ux4 pk;
      pk[0] = cvtpk(h[0], h[1]); pk[1] = cvtpk(h[2], h[3]);
      pk[2] = cvtpk(h[4], h[5]); pk[3] = cvtpk(h[6], h[7]);
      afr[mt][kk] = *(bf8*)&pk;
    }
  }
  __syncthreads();
  // hoist all B fragments to registers (block-uniform cw2 tiles; 72 VGPRs)
  bf8 bfr[6][3];
#pragma unroll
  for (int jt = 0; jt < 6; ++jt)
#pragma unroll
    for (int kk = 0; kk < 3; ++kk)
      bfr[jt][kk] = *(const bf8*)&Ws[((jt * 3 + kk) * 64 + lane) * 8];
  float part[4][4] = {};
#pragma unroll
  for (int jt = 0; jt < 6; ++jt) {
    const float cb2v = cb2[jt * 16 + lrow];
    const float cw3v = cw3[jt * 16 + lrow];
#pragma unroll
    for (int mt = 0; mt < 4; ++mt) {
      fx4 acc{};
      acc = __builtin_amdgcn_mfma_f32_16x16x32_bf16(afr[mt][0], bfr[jt][0], acc, 0, 0, 0);
      acc = __builtin_amdgcn_mfma_f32_16x16x32_bf16(afr[mt][1], bfr[jt][1], acc, 0, 0, 0);
      acc = __builtin_amdgcn_mfma_f32_16x16x32_bf16(afr[mt][2], bfr[jt][2], acc, 0, 0, 0);
#pragma unroll
      for (int r = 0; r < 4; ++r)
        part[mt][r] = fmaf(fmaxf(acc[r] + cb2v, 0.f), cw3v, part[mt][r]);
    }
  }
  const float cb3v = cb3[0];
#pragma unroll
  for (int mt = 0; mt < 4; ++mt) {
#pragma unroll
    for (int r = 0; r < 4; ++r) {
      part[mt][r] += __shfl_xor(part[mt][r], 1);
      part[mt][r] += __shfl_xor(part[mt][r], 2);
      part[mt][r] += __shfl_xor(part[mt][r], 4);
      part[mt][r] += __shfl_xor(part[mt][r], 8);
    }
    float pv2 = part[mt][0];
    pv2 = (lrow == 1) ? part[mt][1] : pv2;
    pv2 = (lrow == 2) ? part[mt][2] : pv2;
    pv2 = (lrow == 3) ? part[mt][3] : pv2;
    if (lrow < 4) {
      const int j = mt * 16 + g16 * 4 + lrow;
      pbias[((size_t)bg * 576 + i) * 64 + j] = pv2 + cb3v;
    }
  }
}

// ---------------- attention: 4 lanes per query, 16 keys each; shfl-reduce softmax & PV
__global__ __launch_bounds__(256, 3) void k_attn(const unsigned short* __restrict__ qT,
                                                 const float* __restrict__ kT,
                                                 const float* __restrict__ vT,
                                                 const float* __restrict__ pbias,
                                                 unsigned short* __restrict__ aoT) {
  __shared__ __align__(16) float kls[3072];
  __shared__ __align__(16) float vls[3072];
  const int t = threadIdx.x;
  const int ic = blockIdx.x, h = blockIdx.y, b = blockIdx.z;
  const int bg = b * 8 + h;
#pragma unroll
  for (int r = 0; r < 3; ++r) {
    const int idx = t + r * 256;
    ((fx4*)kls)[idx] = ((const fx4*)(kT + (size_t)bg * 3072))[idx];
    ((fx4*)vls)[idx] = ((const fx4*)(vT + (size_t)bg * 3072))[idx];
  }
  __syncthreads();
  const int qi = ic * 64 + (t >> 2);
  const int kg = t & 3;
  const unsigned short* qp = qT + ((size_t)b * 576 + qi) * 384 + h * 48;
  const float scale = 0.14433756729740643f;  // 48^-0.5
  float q[48];
#pragma unroll
  for (int c8 = 0; c8 < 6; ++c8) {
    ux4 u = *(const ux4*)(qp + c8 * 8);
    float va[8]; unp8(u, va);
#pragma unroll
    for (int e = 0; e < 8; ++e) q[c8 * 8 + e] = va[e] * scale;
  }
  float s[16];
  const float* kbase = kls + kg * 16 * 48;
#pragma unroll
  for (int it = 0; it < 16; ++it) {
    const fx4* kr = (const fx4*)(kbase + it * 48);
    float a0 = 0.f, a1 = 0.f;
#pragma unroll
    for (int d4 = 0; d4 < 6; ++d4) {
      fx4 k0 = kr[2 * d4], k1 = kr[2 * d4 + 1];
      a0 = fmaf(q[8 * d4 + 0], k0[0], a0); a0 = fmaf(q[8 * d4 + 1], k0[1], a0);
      a0 = fmaf(q[8 * d4 + 2], k0[2], a0); a0 = fmaf(q[8 * d4 + 3], k0[3], a0);
      a1 = fmaf(q[8 * d4 + 4], k1[0], a1); a1 = fmaf(q[8 * d4 + 5], k1[1], a1);
      a1 = fmaf(q[8 * d4 + 6], k1[2], a1); a1 = fmaf(q[8 * d4 + 7], k1[3], a1);
    }
    s[it] = a0 + a1;
  }
  const float* bp = pbias + ((size_t)bg * 576 + qi) * 64 + kg * 16;
#pragma unroll
  for (int i4 = 0; i4 < 4; ++i4) {
    fx4 bv = ((const fx4*)bp)[i4];
    s[i4 * 4 + 0] += bv[0]; s[i4 * 4 + 1] += bv[1];
    s[i4 * 4 + 2] += bv[2]; s[i4 * 4 + 3] += bv[3];
  }
  float mx = s[0];
#pragma unroll
  for (int it = 1; it < 16; ++it) mx = fmaxf(mx, s[it]);
  mx = fmaxf(mx, __shfl_xor(mx, 1));
  mx = fmaxf(mx, __shfl_xor(mx, 2));
  float sum = 0.f;
#pragma unroll
  for (int it = 0; it < 16; ++it) { s[it] = __expf(s[it] - mx); sum += s[it]; }
  sum += __shfl_xor(sum, 1);
  sum += __shfl_xor(sum, 2);
  const float inv = 1.f / sum;
#pragma unroll
  for (int it = 0; it < 16; ++it) s[it] *= inv;
  float acc[48];
#pragma unroll
  for (int d = 0; d < 48; ++d) acc[d] = 0.f;
  const float* vbase = vls + kg * 16 * 48;
#pragma unroll
  for (int it = 0; it < 16; ++it) {
    const float p = s[it];
    const fx4* vr = (const fx4*)(vbase + it * 48);
#pragma unroll
    for (int d4 = 0; d4 < 12; ++d4) {
      fx4 v = vr[d4];
      acc[d4 * 4 + 0] = fmaf(p, v[0], acc[d4 * 4 + 0]);
      acc[d4 * 4 + 1] = fmaf(p, v[1], acc[d4 * 4 + 1]);
      acc[d4 * 4 + 2] = fmaf(p, v[2], acc[d4 * 4 + 2]);
      acc[d4 * 4 + 3] = fmaf(p, v[3], acc[d4 * 4 + 3]);
    }
  }
#pragma unroll
  for (int d = 0; d < 48; ++d) {
    acc[d] += __shfl_xor(acc[d], 1);
    acc[d] += __shfl_xor(acc[d], 2);
  }
  unsigned* op32 = (unsigned*)(aoT + ((size_t)b * 576 + qi) * 384 + h * 48);
  if (kg == 0) {
#pragma unroll
    for (int p2 = 0; p2 < 6; ++p2) op32[p2] = cvtpk(acc[p2 * 2], acc[p2 * 2 + 1]);
  } else if (kg == 1) {
#pragma unroll
    for (int p2 = 0; p2 < 6; ++p2) op32[6 + p2] = cvtpk(acc[12 + p2 * 2], acc[13 + p2 * 2]);
  } else if (kg == 2) {
#pragma unroll
    for (int p2 = 0; p2 < 6; ++p2) op32[12 + p2] = cvtpk(acc[24 + p2 * 2], acc[25 + p2 * 2]);
  } else {
#pragma unroll
    for (int p2 = 0; p2 < 6; ++p2) op32[18 + p2] = cvtpk(acc[36 + p2 * 2], acc[37 + p2 * 2]);
  }
}

extern "C" void kernel_launch(void* const* d_in, const int* in_sizes, int n_in,
                              void* d_out, int out_size, void* d_ws, size_t ws_size,
                              hipStream_t stream) {
  (void)in_sizes; (void)n_in; (void)out_size; (void)ws_size;
  const float* x    = (const float*)d_in[0];
  const float* W1   = (const float*)d_in[1];
  const float* W2   = (const float*)d_in[2];
  const float* W3   = (const float*)d_in[3];
  const float* W4   = (const float*)d_in[4];
  const float* Wq   = (const float*)d_in[5];
  const float* Wk   = (const float*)d_in[6];
  const float* Wv   = (const float*)d_in[7];
  const float* Wdw  = (const float*)d_in[8];
  const float* bdw  = (const float*)d_in[9];
  const float* Wpw  = (const float*)d_in[10];
  const float* cw1  = (const float*)d_in[11];
  const float* cb1  = (const float*)d_in[12];
  const float* cw2  = (const float*)d_in[13];
  const float* cb2  = (const float*)d_in[14];
  const float* cw3  = (const float*)d_in[15];
  const float* cb3  = (const float*)d_in[16];
  const float* Wout = (const float*)d_in[17];
  const float* bout = (const float*)d_in[18];

  char* ws = (char*)d_ws;
  size_t off = 0;
  auto alloc = [&](size_t bytes) {
    void* p = ws + off;
    off += (bytes + 255) & ~(size_t)255;
    return p;
  };
  unsigned short* xT  = (unsigned short*)alloc((size_t)4 * 576 * 1536 * 2);
  unsigned short* h1T = (unsigned short*)alloc((size_t)4 * 576 * 768 * 2);
  unsigned short* h2T = (unsigned short*)alloc((size_t)4 * 576 * 384 * 2);
  unsigned short* qT  = (unsigned short*)alloc((size_t)4 * 576 * 384 * 2);
  unsigned short* aoT = (unsigned short*)alloc((size_t)4 * 576 * 384 * 2);
  unsigned short* AT  = (unsigned short*)alloc((size_t)4 * 576 * 384 * 2);
  unsigned short* h3T = (unsigned short*)alloc((size_t)4 * 576 * 768 * 2);
  float* vgrid = (float*)alloc((size_t)32 * 64 * 2 * 4);
  unsigned short* kvT = (unsigned short*)alloc((size_t)32 * 64 * 48 * 2);
  float* kTb  = (float*)alloc((size_t)32 * 64 * 48 * 4);
  float* vTb  = (float*)alloc((size_t)32 * 64 * 48 * 4);
  float* pbias = (float*)alloc((size_t)32 * 576 * 64 * 4);
  unsigned short* Wcvt = (unsigned short*)alloc((size_t)3105792 * 2);  // bf16 weights
  const unsigned short* W1b   = Wcvt;
  const unsigned short* W2b   = Wcvt + 1179648;
  const unsigned short* W3b   = Wcvt + 1474560;
  const unsigned short* W4b   = Wcvt + 1769472;
  const unsigned short* Woutb = Wcvt + 2949120;
  const unsigned short* cw2b  = Wcvt + 3096576;

  k_wconv<<<6066, 256, 0, stream>>>(W1, W2, W3, W4, Wout, cw2, (unsigned*)Wcvt);
  k_transpose<<<dim3(24, 9, 4), 256, 0, stream>>>(x, xT);
  k_gemm<64, false, false><<<dim3(12, 9, 4), 256, 0, stream>>>(xT, W1b, nullptr, nullptr, h1T, 1536, 768);
  k_gemm<64, false, false><<<dim3(6, 9, 4), 256, 0, stream>>>(h1T, W2b, nullptr, nullptr, h2T, 768, 384);
  k_qproj<<<3456, 256, 0, stream>>>(h2T, Wq, qT);
  k_offsets<<<32, 64, 0, stream>>>(qT, Wdw, bdw, Wpw, vgrid);
  k_gsample<<<32, 64, 0, stream>>>(h2T, vgrid, kvT);
  k_kvproj<<<32, 256, 0, stream>>>(kvT, Wk, Wv, kTb, vTb);
  k_cpb<<<dim3(144, 32), 256, 0, stream>>>(vgrid, cw1, cb1, cw2b, cb2, cw3, cb3, pbias);
  k_attn<<<dim3(9, 8, 4), 256, 0, stream>>>(qT, kTb, vTb, pbias, aoT);
  k_gemm<64, true, false><<<dim3(6, 9, 4), 256, 0, stream>>>(aoT, Woutb, bout, nullptr, AT, 384, 384);
  k_gemm<64, false, false><<<dim3(12, 9, 4), 256, 0, stream>>>(AT, W3b, nullptr, nullptr, h3T, 384, 768);
  k_gemm<128, false, true><<<dim3(12, 9, 4), 256, 0, stream>>>(h3T, W4b, nullptr, x, d_out, 768, 1536);
}

// Round 6
// 227.493 us; speedup vs baseline: 1.2454x; 1.0077x over previous
//
#include <hip/hip_runtime.h>

typedef float        fx4 __attribute__((ext_vector_type(4)));
typedef unsigned int ux4 __attribute__((ext_vector_type(4)));
typedef short        bf8 __attribute__((ext_vector_type(8)));

#define DEVI static __device__ __forceinline__

DEVI unsigned f2bf1(float f) {
  union { float f; unsigned u; } v; v.f = f;
  return (v.u + 0x7FFFu + ((v.u >> 16) & 1u)) >> 16;
}
DEVI float bf2f(unsigned h) {
  union { unsigned u; float f; } v; v.u = h << 16; return v.f;
}
DEVI unsigned cvtpk(float lo, float hi) {
  unsigned r;
  asm("v_cvt_pk_bf16_f32 %0, %1, %2" : "=v"(r) : "v"(lo), "v"(hi));
  return r;
}
DEVI void unp8(ux4 u, float* o) {
  o[0] = bf2f(u[0] & 0xffffu); o[1] = bf2f(u[0] >> 16);
  o[2] = bf2f(u[1] & 0xffffu); o[3] = bf2f(u[1] >> 16);
  o[4] = bf2f(u[2] & 0xffffu); o[5] = bf2f(u[2] >> 16);
  o[6] = bf2f(u[3] & 0xffffu); o[7] = bf2f(u[3] >> 16);
}
DEVI void gload16(const void* g, void* l) {
  __builtin_amdgcn_global_load_lds(
      (const __attribute__((address_space(1))) unsigned*)(uintptr_t)(g),
      (__attribute__((address_space(3))) unsigned*)(unsigned)(uintptr_t)(l),
      16, 0, 0);
}

// ---------------- weight pre-convert: f32 -> bf16 (W1,W2,W3,W4,Wout,cw2 concatenated)
__global__ __launch_bounds__(256) void k_wconv(const float* __restrict__ W1,
                                               const float* __restrict__ W2,
                                               const float* __restrict__ W3,
                                               const float* __restrict__ W4,
                                               const float* __restrict__ Wout,
                                               const float* __restrict__ cw2,
                                               unsigned* __restrict__ dst) {
  const size_t p = (size_t)blockIdx.x * 256 + threadIdx.x;  // pair index
  const float* s; size_t base;
  if (p < 589824)       { s = W1;   base = 0; }
  else if (p < 737280)  { s = W2;   base = 589824; }
  else if (p < 884736)  { s = W3;   base = 737280; }
  else if (p < 1474560) { s = W4;   base = 884736; }
  else if (p < 1548288) { s = Wout; base = 1474560; }
  else if (p < 1552896) { s = cw2;  base = 1548288; }
  else return;
  const size_t lp = p - base;
  dst[p] = cvtpk(s[lp * 2], s[lp * 2 + 1]);
}

// ---------------- transpose + bf16 convert: x (4,1536,576) f32 -> xT (4,576,1536) bf16
__global__ __launch_bounds__(256) void k_transpose(const float* __restrict__ x,
                                                   unsigned short* __restrict__ xT) {
  __shared__ float tile[64][65];
  const int t = threadIdx.x;
  const int b = blockIdx.z, c0 = blockIdx.x * 64, p0 = blockIdx.y * 64;
  const int tl = t & 63, th = t >> 6;
#pragma unroll
  for (int r = 0; r < 16; ++r) {
    int c = th * 16 + r;
    tile[c][tl] = x[((size_t)b * 1536 + c0 + c) * 576 + p0 + tl];
  }
  __syncthreads();
#pragma unroll
  for (int r = 0; r < 16; ++r) {
    int p = th * 16 + r;
    xT[((size_t)b * 576 + p0 + p) * 1536 + c0 + tl] = (unsigned short)f2bf1(tile[tl][p]);
  }
}

// ---------------- bf16 MFMA GEMM, 64 x BN tile, BK=64, 3-deep pipeline w/ counted vmcnt
// A: bf16 (4,576,K) k-contig; Wb: bf16 (M,K) k-contig; out: bf16 (4,576,M) or FINAL f32 NCHW+resid
// chunk q -> row = (q>>7)*16 + (q&15); k = ((q>>6)&1)*32 + ((q>>4)&3)*8   (fragment-ordered LDS)
#define ROWOF(q) ((((q) >> 7) << 4) + ((q) & 15))
#define KOF(q)   (((((q) >> 6) & 1) << 5) + ((((q) >> 4) & 3) << 3))
template<int BN, bool BIASADD, bool FINAL>
__global__ __launch_bounds__(256, 4) void k_gemm(const unsigned short* __restrict__ A,
                                                 const unsigned short* __restrict__ Wb,
                                                 const float* __restrict__ bias,
                                                 const float* __restrict__ resid,
                                                 void* __restrict__ outp, int K, int M) {
  constexpr int BCH = BN / 32;  // B staging chunks per thread (2|4); A is always 2
  constexpr int NJT = BN / 32;  // 16-col fragments per wave (wave tile 32 x BN/2)
  __shared__ __align__(16) unsigned short As[3][4096];
  __shared__ __align__(16) unsigned short Bs[3][BN * 64];
  const int t = threadIdx.x;
  const int bz = blockIdx.z, j0 = blockIdx.x * BN, i0 = blockIdx.y * 64;
  const int lane = t & 63, wid = t >> 6;
  const int wi = wid >> 1, wj = wid & 1;
  const int lrow = lane & 15, g4 = lane >> 4;

  const unsigned short* pa0 = A + ((size_t)(bz * 576 + i0 + ROWOF(t))) * K + KOF(t);
  const unsigned short* pa1 = A + ((size_t)(bz * 576 + i0 + ROWOF(t + 256))) * K + KOF(t + 256);
  const unsigned short* pb[BCH];
#pragma unroll
  for (int c = 0; c < BCH; ++c) {
    const int q = t + c * 256;
    pb[c] = Wb + ((size_t)(j0 + ROWOF(q))) * K + KOF(q);
  }
  auto stage = [&](int buf, int ko) {
    gload16(pa0 + ko, &As[buf][t * 8]);
    gload16(pa1 + ko, &As[buf][(t + 256) * 8]);
#pragma unroll
    for (int c = 0; c < BCH; ++c) gload16(pb[c] + ko, &Bs[buf][(t + c * 256) * 8]);
  };
  fx4 acc[2][NJT] = {};
  const int nk = K >> 6;
  stage(0, 0);
  if (nk > 1) stage(1, 64);
  int cur = 0;
  for (int ki = 0; ki < nk; ++ki) {
    // wait: oldest stage (buf=cur) landed; keep next stage(s) in flight across the barrier
    if (ki + 1 < nk) {
      if constexpr (BCH == 2) asm volatile("s_waitcnt vmcnt(4)" ::: "memory");
      else                    asm volatile("s_waitcnt vmcnt(6)" ::: "memory");
    } else {
      asm volatile("s_waitcnt vmcnt(0)" ::: "memory");
    }
    __builtin_amdgcn_s_barrier();
    __builtin_amdgcn_sched_barrier(0);
    asm volatile("" ::: "memory");
    if (ki + 2 < nk) {
      int b2 = cur - 1; if (b2 < 0) b2 = 2;  // (cur+2)%3: the buffer consumed in iter ki-1
      stage(b2, (ki + 2) * 64);
    }
    const unsigned short* ab = &As[cur][0];
    const unsigned short* bb = &Bs[cur][0];
#pragma unroll
    for (int kk = 0; kk < 2; ++kk) {
      bf8 a0 = *(const bf8*)(ab + (((wi * 2 + 0) * 2 + kk) * 64 + lane) * 8);
      bf8 a1 = *(const bf8*)(ab + (((wi * 2 + 1) * 2 + kk) * 64 + lane) * 8);
#pragma unroll
      for (int jt = 0; jt < NJT; ++jt) {
        bf8 b = *(const bf8*)(bb + (((wj * NJT + jt) * 2 + kk) * 64 + lane) * 8);
        acc[0][jt] = __builtin_amdgcn_mfma_f32_16x16x32_bf16(a0, b, acc[0][jt], 0, 0, 0);
        acc[1][jt] = __builtin_amdgcn_mfma_f32_16x16x32_bf16(a1, b, acc[1][jt], 0, 0, 0);
      }
    }
    cur = (cur == 2) ? 0 : cur + 1;
  }
#pragma unroll
  for (int it = 0; it < 2; ++it) {
    const int row0 = i0 + wi * 32 + it * 16 + g4 * 4;
#pragma unroll
    for (int jt = 0; jt < NJT; ++jt) {
      fx4 v = acc[it][jt];
      const int m = j0 + wj * (BN / 2) + jt * 16 + lrow;
      if (BIASADD) {
        float bv = bias[m];
        v[0] += bv; v[1] += bv; v[2] += bv; v[3] += bv;
      }
      if (FINAL) {
        const fx4 xr = *(const fx4*)(resid + ((size_t)bz * M + m) * 576 + row0);
        fx4 ov;
        ov[0] = fmaxf(v[0] + xr[0], 0.f); ov[1] = fmaxf(v[1] + xr[1], 0.f);
        ov[2] = fmaxf(v[2] + xr[2], 0.f); ov[3] = fmaxf(v[3] + xr[3], 0.f);
        *(fx4*)((float*)outp + ((size_t)bz * M + m) * 576 + row0) = ov;
      } else {
        unsigned short* o = (unsigned short*)outp;
#pragma unroll
        for (int r = 0; r < 4; ++r)
          o[((size_t)(bz * 576) + row0 + r) * M + m] = (unsigned short)f2bf1(fmaxf(v[r], 0.f));
      }
    }
  }
}
#undef ROWOF
#undef KOF

// ---------------- grouped 1x1 conv for q
__global__ __launch_bounds__(256) void k_qproj(const unsigned short* __restrict__ h2T,
                                               const float* __restrict__ Wq,
                                               unsigned short* __restrict__ qT) {
  const int idx = blockIdx.x * 256 + threadIdx.x;
  const int c = idx % 384;
  const int n = idx / 384;
  const int g = c / 48, o = c % 48;
  const unsigned short* ap = h2T + (size_t)n * 384 + g * 48;
  const float* wp = Wq + ((size_t)g * 48 + o) * 48;
  float acc = 0.f;
#pragma unroll
  for (int c8 = 0; c8 < 6; ++c8) {
    ux4 u = *(const ux4*)(ap + c8 * 8);
    float va[8]; unp8(u, va);
    fx4 w0 = *(const fx4*)(wp + c8 * 8);
    fx4 w1 = *(const fx4*)(wp + c8 * 8 + 4);
    acc = fmaf(va[0], w0[0], acc); acc = fmaf(va[1], w0[1], acc);
    acc = fmaf(va[2], w0[2], acc); acc = fmaf(va[3], w0[3], acc);
    acc = fmaf(va[4], w1[0], acc); acc = fmaf(va[5], w1[1], acc);
    acc = fmaf(va[6], w1[2], acc); acc = fmaf(va[7], w1[3], acc);
  }
  qT[(size_t)n * 384 + c] = (unsigned short)f2bf1(acc);
}

// ---------------- offsets: depthwise 3x3/s3 -> gelu -> 1x1 (2) -> tanh*4 -> normalized grid
__global__ __launch_bounds__(64, 2) void k_offsets(const unsigned short* __restrict__ qT,
                                                   const float* __restrict__ Wdw,
                                                   const float* __restrict__ bdw,
                                                   const float* __restrict__ Wpw,
                                                   float* __restrict__ vgrid) {
  const int bg = blockIdx.x, t = threadIdx.x;
  const int b = bg >> 3, g = bg & 7;
  const int oy = t >> 3, ox = t & 7;
  float s[48];
#pragma unroll
  for (int ch = 0; ch < 48; ++ch) s[ch] = bdw[ch];
#pragma unroll
  for (int ky = 0; ky < 3; ++ky) {
#pragma unroll
    for (int kx = 0; kx < 3; ++kx) {
      const unsigned short* rp =
          qT + ((size_t)b * 576 + (oy * 3 + ky) * 24 + ox * 3 + kx) * 384 + g * 48;
      const int tap = ky * 3 + kx;
#pragma unroll
      for (int c8 = 0; c8 < 6; ++c8) {
        ux4 u = *(const ux4*)(rp + c8 * 8);
        float va[8]; unp8(u, va);
#pragma unroll
        for (int e = 0; e < 8; ++e)
          s[c8 * 8 + e] = fmaf(va[e], Wdw[(c8 * 8 + e) * 9 + tap], s[c8 * 8 + e]);
      }
    }
  }
  float a0 = 0.f, a1 = 0.f;
#pragma unroll
  for (int ch = 0; ch < 48; ++ch) {
    float z = s[ch];
    float ge = 0.5f * z * (1.f + erff(z * 0.70710678118654752f));
    a0 = fmaf(ge, Wpw[ch], a0);
    a1 = fmaf(ge, Wpw[48 + ch], a1);
  }
  const float off0 = tanhf(a0) * 4.f;
  const float off1 = tanhf(a1) * 4.f;
  vgrid[bg * 128 + t * 2 + 0] = ((float)ox + off0) * (2.f / 7.f) - 1.f;
  vgrid[bg * 128 + t * 2 + 1] = ((float)oy + off1) * (2.f / 7.f) - 1.f;
}

// ---------------- bilinear grid sample (zeros padding, align_corners=False)
__global__ __launch_bounds__(64, 2) void k_gsample(const unsigned short* __restrict__ h2T,
                                                   const float* __restrict__ vgrid,
                                                   unsigned short* __restrict__ kvT) {
  const int bg = blockIdx.x, j = threadIdx.x;
  const int b = bg >> 3, g = bg & 7;
  const float nx = vgrid[bg * 128 + j * 2 + 0];
  const float ny = vgrid[bg * 128 + j * 2 + 1];
  const float xs = ((nx + 1.f) * 24.f - 1.f) * 0.5f;
  const float ys = ((ny + 1.f) * 24.f - 1.f) * 0.5f;
  const float x0f = floorf(xs), y0f = floorf(ys);
  const float wx = xs - x0f, wy = ys - y0f;
  const int x0 = (int)x0f, y0 = (int)y0f;
  float acc[48];
#pragma unroll
  for (int ch = 0; ch < 48; ++ch) acc[ch] = 0.f;
  const float tw[4] = {(1.f - wx) * (1.f - wy), wx * (1.f - wy), (1.f - wx) * wy, wx * wy};
  const int tx[4] = {x0, x0 + 1, x0, x0 + 1};
  const int ty[4] = {y0, y0, y0 + 1, y0 + 1};
#pragma unroll
  for (int tp = 0; tp < 4; ++tp) {
    const int ix = tx[tp], iy = ty[tp];
    const float w = tw[tp] * ((ix >= 0 && ix < 24 && iy >= 0 && iy < 24) ? 1.f : 0.f);
    const int cx = min(max(ix, 0), 23), cy = min(max(iy, 0), 23);
    const unsigned short* rp = h2T + ((size_t)b * 576 + cy * 24 + cx) * 384 + g * 48;
#pragma unroll
    for (int c8 = 0; c8 < 6; ++c8) {
      ux4 u = *(const ux4*)(rp + c8 * 8);
      float va[8]; unp8(u, va);
#pragma unroll
      for (int e = 0; e < 8; ++e) acc[c8 * 8 + e] = fmaf(va[e], w, acc[c8 * 8 + e]);
    }
  }
  unsigned short* op = kvT + ((size_t)bg * 64 + j) * 48;
#pragma unroll
  for (int c2 = 0; c2 < 24; ++c2)
    ((unsigned*)op)[c2] = cvtpk(acc[2 * c2], acc[2 * c2 + 1]);
}

// ---------------- k/v grouped 1x1 conv on kv (f32 out)
__global__ __launch_bounds__(256) void k_kvproj(const unsigned short* __restrict__ kvT,
                                                const float* __restrict__ Wk,
                                                const float* __restrict__ Wv,
                                                float* __restrict__ kT, float* __restrict__ vT) {
  const int bg = blockIdx.x, t = threadIdx.x;
  const int g = bg & 7;
  for (int idx = t; idx < 64 * 48; idx += 256) {
    const int j = idx / 48, o = idx % 48;
    const unsigned short* rp = kvT + ((size_t)bg * 64 + j) * 48;
    const float* wkp = Wk + ((size_t)g * 48 + o) * 48;
    const float* wvp = Wv + ((size_t)g * 48 + o) * 48;
    float ak = 0.f, av = 0.f;
#pragma unroll
    for (int c8 = 0; c8 < 6; ++c8) {
      ux4 u = *(const ux4*)(rp + c8 * 8);
      float va[8]; unp8(u, va);
      fx4 wk0 = *(const fx4*)(wkp + c8 * 8); fx4 wk1 = *(const fx4*)(wkp + c8 * 8 + 4);
      fx4 wv0 = *(const fx4*)(wvp + c8 * 8); fx4 wv1 = *(const fx4*)(wvp + c8 * 8 + 4);
#pragma unroll
      for (int e = 0; e < 4; ++e) {
        ak = fmaf(va[e], wk0[e], ak); ak = fmaf(va[4 + e], wk1[e], ak);
        av = fmaf(va[e], wv0[e], av); av = fmaf(va[4 + e], wv1[e], av);
      }
    }
    kT[(size_t)bg * 3072 + idx] = ak;
    vT[(size_t)bg * 3072 + idx] = av;
  }
}

// ---------------- CPB bias MLP (2 -> 96 -> 96 -> 1): mt-outer streaming, peak live ~60 VGPR
// r3-r5 post-mortem: allocator never grants >88 VGPRs here regardless of bounds; the old
// structure (afr[4][3]=48 + bfr hoist=72 + part=16) spilled to scratch/LDS every round.
// This version keeps only afr[3] (12) + streamed B-frag (12) + part (4) live per mt-tile.
// Opaque offsets (asm "+v") defeat LICM re-hoisting of mt-invariant cw1/cb1/Ws loads.
__global__ __launch_bounds__(256) void k_cpb(const float* __restrict__ vgrid,
                                             const float* __restrict__ cw1,
                                             const float* __restrict__ cb1,
                                             const unsigned short* __restrict__ cw2b,
                                             const float* __restrict__ cb2,
                                             const float* __restrict__ cw3,
                                             const float* __restrict__ cb3,
                                             float* __restrict__ pbias) {
  __shared__ __align__(16) unsigned short Ws[1152 * 8];  // 18 subtiles (6 jt x 3 kk)
  const int t = threadIdx.x;
  const int bg = blockIdx.y;
  const int wid = t >> 6, lane = t & 63;
  const int lrow = lane & 15, g16 = lane >> 4;
  const int i = blockIdx.x * 4 + wid;
  // stage cw2b -> fragment-ordered LDS
#pragma unroll
  for (int rep = 0; rep < 5; ++rep) {
    const int q = t + rep * 256;
    if (q < 1152) {
      const int s = q >> 6, l = q & 63;
      const int jt = s / 3, kk = s - jt * 3;
      const int n = jt * 16 + (l & 15);
      const int k = kk * 32 + ((l >> 4) & 3) * 8;
      gload16(cw2b + (size_t)n * 96 + k, &Ws[q * 8]);
    }
  }
  const float qnx = (float)(i % 24) * (2.f / 23.f) - 1.f;
  const float qny = (float)(i / 24) * (2.f / 23.f) - 1.f;
  const float cb3v = cb3[0];
  __syncthreads();
#pragma unroll 1
  for (int mt = 0; mt < 4; ++mt) {
    // opaque zero offsets: block LICM from hoisting loop-invariant loads out of mt loop
    int c1o = 0, wso = 0;
    asm volatile("" : "+v"(c1o), "+v"(wso));
    // layer-1 for this j-tile (j = mt*16 + lrow)
    const int j = mt * 16 + lrow;
    const float kx = vgrid[bg * 128 + j * 2 + 0];
    const float ky = vgrid[bg * 128 + j * 2 + 1];
    const float pu = qnx - kx, pv = qny - ky;
    const float uu = copysignf(__logf(1.f + fabsf(pu)), pu);
    const float vv = copysignf(__logf(1.f + fabsf(pv)), pv);
    bf8 afr[3];
#pragma unroll
    for (int kk = 0; kk < 3; ++kk) {
      const int kb = kk * 32 + g16 * 8;
      fx4 w0 = *(const fx4*)(cw1 + c1o + kb * 2);
      fx4 w1 = *(const fx4*)(cw1 + c1o + kb * 2 + 4);
      fx4 w2 = *(const fx4*)(cw1 + c1o + kb * 2 + 8);
      fx4 w3 = *(const fx4*)(cw1 + c1o + kb * 2 + 12);
      fx4 b0 = *(const fx4*)(cb1 + c1o + kb);
      fx4 b1 = *(const fx4*)(cb1 + c1o + kb + 4);
      float h[8];
      h[0] = fmaxf(fmaf(w0[0], uu, fmaf(w0[1], vv, b0[0])), 0.f);
      h[1] = fmaxf(fmaf(w0[2], uu, fmaf(w0[3], vv, b0[1])), 0.f);
      h[2] = fmaxf(fmaf(w1[0], uu, fmaf(w1[1], vv, b0[2])), 0.f);
      h[3] = fmaxf(fmaf(w1[2], uu, fmaf(w1[3], vv, b0[3])), 0.f);
      h[4] = fmaxf(fmaf(w2[0], uu, fmaf(w2[1], vv, b1[0])), 0.f);
      h[5] = fmaxf(fmaf(w2[2], uu, fmaf(w2[3], vv, b1[1])), 0.f);
      h[6] = fmaxf(fmaf(w3[0], uu, fmaf(w3[1], vv, b1[2])), 0.f);
      h[7] = fmaxf(fmaf(w3[2], uu, fmaf(w3[3], vv, b1[3])), 0.f);
      ux4 pk;
      pk[0] = cvtpk(h[0], h[1]); pk[1] = cvtpk(h[2], h[3]);
      pk[2] = cvtpk(h[4], h[5]); pk[3] = cvtpk(h[6], h[7]);
      afr[kk] = *(bf8*)&pk;
    }
    // layer-2 MFMA streaming B from LDS + fused layer-3 epilogue
    fx4 part = {0.f, 0.f, 0.f, 0.f};
#pragma unroll
    for (int jt = 0; jt < 6; ++jt) {
      bf8 bf0 = *(const bf8*)&Ws[wso + ((jt * 3 + 0) * 64 + lane) * 8];
      bf8 bf1 = *(const bf8*)&Ws[wso + ((jt * 3 + 1) * 64 + lane) * 8];
      bf8 bf2 = *(const bf8*)&Ws[wso + ((jt * 3 + 2) * 64 + lane) * 8];
      fx4 acc{};
      acc = __builtin_amdgcn_mfma_f32_16x16x32_bf16(afr[0], bf0, acc, 0, 0, 0);
      acc = __builtin_amdgcn_mfma_f32_16x16x32_bf16(afr[1], bf1, acc, 0, 0, 0);
      acc = __builtin_amdgcn_mfma_f32_16x16x32_bf16(afr[2], bf2, acc, 0, 0, 0);
      const float cb2v = cb2[jt * 16 + lrow];
      const float cw3v = cw3[jt * 16 + lrow];
#pragma unroll
      for (int r = 0; r < 4; ++r)
        part[r] = fmaf(fmaxf(acc[r] + cb2v, 0.f), cw3v, part[r]);
    }
#pragma unroll
    for (int r = 0; r < 4; ++r) {
      part[r] += __shfl_xor(part[r], 1);
      part[r] += __shfl_xor(part[r], 2);
      part[r] += __shfl_xor(part[r], 4);
      part[r] += __shfl_xor(part[r], 8);
    }
    float pv2 = part[0];
    pv2 = (lrow == 1) ? part[1] : pv2;
    pv2 = (lrow == 2) ? part[2] : pv2;
    pv2 = (lrow == 3) ? part[3] : pv2;
    if (lrow < 4) {
      const int jo = mt * 16 + g16 * 4 + lrow;
      pbias[((size_t)bg * 576 + i) * 64 + jo] = pv2 + cb3v;
    }
  }
}

// ---------------- attention: 4 lanes per query, 16 keys each; shfl-reduce softmax & PV
__global__ __launch_bounds__(256, 3) void k_attn(const unsigned short* __restrict__ qT,
                                                 const float* __restrict__ kT,
                                                 const float* __restrict__ vT,
                                                 const float* __restrict__ pbias,
                                                 unsigned short* __restrict__ aoT) {
  __shared__ __align__(16) float kls[3072];
  __shared__ __align__(16) float vls[3072];
  const int t = threadIdx.x;
  const int ic = blockIdx.x, h = blockIdx.y, b = blockIdx.z;
  const int bg = b * 8 + h;
#pragma unroll
  for (int r = 0; r < 3; ++r) {
    const int idx = t + r * 256;
    ((fx4*)kls)[idx] = ((const fx4*)(kT + (size_t)bg * 3072))[idx];
    ((fx4*)vls)[idx] = ((const fx4*)(vT + (size_t)bg * 3072))[idx];
  }
  __syncthreads();
  const int qi = ic * 64 + (t >> 2);
  const int kg = t & 3;
  const unsigned short* qp = qT + ((size_t)b * 576 + qi) * 384 + h * 48;
  const float scale = 0.14433756729740643f;  // 48^-0.5
  float q[48];
#pragma unroll
  for (int c8 = 0; c8 < 6; ++c8) {
    ux4 u = *(const ux4*)(qp + c8 * 8);
    float va[8]; unp8(u, va);
#pragma unroll
    for (int e = 0; e < 8; ++e) q[c8 * 8 + e] = va[e] * scale;
  }
  float s[16];
  const float* kbase = kls + kg * 16 * 48;
#pragma unroll
  for (int it = 0; it < 16; ++it) {
    const fx4* kr = (const fx4*)(kbase + it * 48);
    float a0 = 0.f, a1 = 0.f;
#pragma unroll
    for (int d4 = 0; d4 < 6; ++d4) {
      fx4 k0 = kr[2 * d4], k1 = kr[2 * d4 + 1];
      a0 = fmaf(q[8 * d4 + 0], k0[0], a0); a0 = fmaf(q[8 * d4 + 1], k0[1], a0);
      a0 = fmaf(q[8 * d4 + 2], k0[2], a0); a0 = fmaf(q[8 * d4 + 3], k0[3], a0);
      a1 = fmaf(q[8 * d4 + 4], k1[0], a1); a1 = fmaf(q[8 * d4 + 5], k1[1], a1);
      a1 = fmaf(q[8 * d4 + 6], k1[2], a1); a1 = fmaf(q[8 * d4 + 7], k1[3], a1);
    }
    s[it] = a0 + a1;
  }
  const float* bp = pbias + ((size_t)bg * 576 + qi) * 64 + kg * 16;
#pragma unroll
  for (int i4 = 0; i4 < 4; ++i4) {
    fx4 bv = ((const fx4*)bp)[i4];
    s[i4 * 4 + 0] += bv[0]; s[i4 * 4 + 1] += bv[1];
    s[i4 * 4 + 2] += bv[2]; s[i4 * 4 + 3] += bv[3];
  }
  float mx = s[0];
#pragma unroll
  for (int it = 1; it < 16; ++it) mx = fmaxf(mx, s[it]);
  mx = fmaxf(mx, __shfl_xor(mx, 1));
  mx = fmaxf(mx, __shfl_xor(mx, 2));
  float sum = 0.f;
#pragma unroll
  for (int it = 0; it < 16; ++it) { s[it] = __expf(s[it] - mx); sum += s[it]; }
  sum += __shfl_xor(sum, 1);
  sum += __shfl_xor(sum, 2);
  const float inv = 1.f / sum;
#pragma unroll
  for (int it = 0; it < 16; ++it) s[it] *= inv;
  float acc[48];
#pragma unroll
  for (int d = 0; d < 48; ++d) acc[d] = 0.f;
  const float* vbase = vls + kg * 16 * 48;
#pragma unroll
  for (int it = 0; it < 16; ++it) {
    const float p = s[it];
    const fx4* vr = (const fx4*)(vbase + it * 48);
#pragma unroll
    for (int d4 = 0; d4 < 12; ++d4) {
      fx4 v = vr[d4];
      acc[d4 * 4 + 0] = fmaf(p, v[0], acc[d4 * 4 + 0]);
      acc[d4 * 4 + 1] = fmaf(p, v[1], acc[d4 * 4 + 1]);
      acc[d4 * 4 + 2] = fmaf(p, v[2], acc[d4 * 4 + 2]);
      acc[d4 * 4 + 3] = fmaf(p, v[3], acc[d4 * 4 + 3]);
    }
  }
#pragma unroll
  for (int d = 0; d < 48; ++d) {
    acc[d] += __shfl_xor(acc[d], 1);
    acc[d] += __shfl_xor(acc[d], 2);
  }
  unsigned* op32 = (unsigned*)(aoT + ((size_t)b * 576 + qi) * 384 + h * 48);
  if (kg == 0) {
#pragma unroll
    for (int p2 = 0; p2 < 6; ++p2) op32[p2] = cvtpk(acc[p2 * 2], acc[p2 * 2 + 1]);
  } else if (kg == 1) {
#pragma unroll
    for (int p2 = 0; p2 < 6; ++p2) op32[6 + p2] = cvtpk(acc[12 + p2 * 2], acc[13 + p2 * 2]);
  } else if (kg == 2) {
#pragma unroll
    for (int p2 = 0; p2 < 6; ++p2) op32[12 + p2] = cvtpk(acc[24 + p2 * 2], acc[25 + p2 * 2]);
  } else {
#pragma unroll
    for (int p2 = 0; p2 < 6; ++p2) op32[18 + p2] = cvtpk(acc[36 + p2 * 2], acc[37 + p2 * 2]);
  }
}

extern "C" void kernel_launch(void* const* d_in, const int* in_sizes, int n_in,
                              void* d_out, int out_size, void* d_ws, size_t ws_size,
                              hipStream_t stream) {
  (void)in_sizes; (void)n_in; (void)out_size; (void)ws_size;
  const float* x    = (const float*)d_in[0];
  const float* W1   = (const float*)d_in[1];
  const float* W2   = (const float*)d_in[2];
  const float* W3   = (const float*)d_in[3];
  const float* W4   = (const float*)d_in[4];
  const float* Wq   = (const float*)d_in[5];
  const float* Wk   = (const float*)d_in[6];
  const float* Wv   = (const float*)d_in[7];
  const float* Wdw  = (const float*)d_in[8];
  const float* bdw  = (const float*)d_in[9];
  const float* Wpw  = (const float*)d_in[10];
  const float* cw1  = (const float*)d_in[11];
  const float* cb1  = (const float*)d_in[12];
  const float* cw2  = (const float*)d_in[13];
  const float* cb2  = (const float*)d_in[14];
  const float* cw3  = (const float*)d_in[15];
  const float* cb3  = (const float*)d_in[16];
  const float* Wout = (const float*)d_in[17];
  const float* bout = (const float*)d_in[18];

  char* ws = (char*)d_ws;
  size_t off = 0;
  auto alloc = [&](size_t bytes) {
    void* p = ws + off;
    off += (bytes + 255) & ~(size_t)255;
    return p;
  };
  unsigned short* xT  = (unsigned short*)alloc((size_t)4 * 576 * 1536 * 2);
  unsigned short* h1T = (unsigned short*)alloc((size_t)4 * 576 * 768 * 2);
  unsigned short* h2T = (unsigned short*)alloc((size_t)4 * 576 * 384 * 2);
  unsigned short* qT  = (unsigned short*)alloc((size_t)4 * 576 * 384 * 2);
  unsigned short* aoT = (unsigned short*)alloc((size_t)4 * 576 * 384 * 2);
  unsigned short* AT  = (unsigned short*)alloc((size_t)4 * 576 * 384 * 2);
  unsigned short* h3T = (unsigned short*)alloc((size_t)4 * 576 * 768 * 2);
  float* vgrid = (float*)alloc((size_t)32 * 64 * 2 * 4);
  unsigned short* kvT = (unsigned short*)alloc((size_t)32 * 64 * 48 * 2);
  float* kTb  = (float*)alloc((size_t)32 * 64 * 48 * 4);
  float* vTb  = (float*)alloc((size_t)32 * 64 * 48 * 4);
  float* pbias = (float*)alloc((size_t)32 * 576 * 64 * 4);
  unsigned short* Wcvt = (unsigned short*)alloc((size_t)3105792 * 2);  // bf16 weights
  const unsigned short* W1b   = Wcvt;
  const unsigned short* W2b   = Wcvt + 1179648;
  const unsigned short* W3b   = Wcvt + 1474560;
  const unsigned short* W4b   = Wcvt + 1769472;
  const unsigned short* Woutb = Wcvt + 2949120;
  const unsigned short* cw2b  = Wcvt + 3096576;

  k_wconv<<<6066, 256, 0, stream>>>(W1, W2, W3, W4, Wout, cw2, (unsigned*)Wcvt);
  k_transpose<<<dim3(24, 9, 4), 256, 0, stream>>>(x, xT);
  k_gemm<64, false, false><<<dim3(12, 9, 4), 256, 0, stream>>>(xT, W1b, nullptr, nullptr, h1T, 1536, 768);
  k_gemm<64, false, false><<<dim3(6, 9, 4), 256, 0, stream>>>(h1T, W2b, nullptr, nullptr, h2T, 768, 384);
  k_qproj<<<3456, 256, 0, stream>>>(h2T, Wq, qT);
  k_offsets<<<32, 64, 0, stream>>>(qT, Wdw, bdw, Wpw, vgrid);
  k_gsample<<<32, 64, 0, stream>>>(h2T, vgrid, kvT);
  k_kvproj<<<32, 256, 0, stream>>>(kvT, Wk, Wv, kTb, vTb);
  k_cpb<<<dim3(144, 32), 256, 0, stream>>>(vgrid, cw1, cb1, cw2b, cb2, cw3, cb3, pbias);
  k_attn<<<dim3(9, 8, 4), 256, 0, stream>>>(qT, kTb, vTb, pbias, aoT);
  k_gemm<64, true, false><<<dim3(6, 9, 4), 256, 0, stream>>>(aoT, Woutb, bout, nullptr, AT, 384, 384);
  k_gemm<64, false, false><<<dim3(12, 9, 4), 256, 0, stream>>>(AT, W3b, nullptr, nullptr, h3T, 384, 768);
  k_gemm<128, false, true><<<dim3(12, 9, 4), 256, 0, stream>>>(h3T, W4b, nullptr, x, d_out, 768, 1536);
}

// Round 7
// 226.672 us; speedup vs baseline: 1.2499x; 1.0036x over previous
//
#include <hip/hip_runtime.h>

typedef float        fx4 __attribute__((ext_vector_type(4)));
typedef float        fx2 __attribute__((ext_vector_type(2)));
typedef unsigned int ux4 __attribute__((ext_vector_type(4)));
typedef short        bf8 __attribute__((ext_vector_type(8)));

#define DEVI static __device__ __forceinline__

DEVI unsigned f2bf1(float f) {
  union { float f; unsigned u; } v; v.f = f;
  return (v.u + 0x7FFFu + ((v.u >> 16) & 1u)) >> 16;
}
DEVI float bf2f(unsigned h) {
  union { unsigned u; float f; } v; v.u = h << 16; return v.f;
}
DEVI unsigned cvtpk(float lo, float hi) {
  unsigned r;
  asm("v_cvt_pk_bf16_f32 %0, %1, %2" : "=v"(r) : "v"(lo), "v"(hi));
  return r;
}
DEVI void unp8(ux4 u, float* o) {
  o[0] = bf2f(u[0] & 0xffffu); o[1] = bf2f(u[0] >> 16);
  o[2] = bf2f(u[1] & 0xffffu); o[3] = bf2f(u[1] >> 16);
  o[4] = bf2f(u[2] & 0xffffu); o[5] = bf2f(u[2] >> 16);
  o[6] = bf2f(u[3] & 0xffffu); o[7] = bf2f(u[3] >> 16);
}
DEVI void gload16(const void* g, void* l) {
  __builtin_amdgcn_global_load_lds(
      (const __attribute__((address_space(1))) unsigned*)(uintptr_t)(g),
      (__attribute__((address_space(3))) unsigned*)(unsigned)(uintptr_t)(l),
      16, 0, 0);
}

// ---------------- weight pre-convert: f32 -> bf16 (W1,W2,W3,W4,Wout,cw2 concatenated)
__global__ __launch_bounds__(256) void k_wconv(const float* __restrict__ W1,
                                               const float* __restrict__ W2,
                                               const float* __restrict__ W3,
                                               const float* __restrict__ W4,
                                               const float* __restrict__ Wout,
                                               const float* __restrict__ cw2,
                                               unsigned* __restrict__ dst) {
  const size_t p = (size_t)blockIdx.x * 256 + threadIdx.x;  // pair index
  const float* s; size_t base;
  if (p < 589824)       { s = W1;   base = 0; }
  else if (p < 737280)  { s = W2;   base = 589824; }
  else if (p < 884736)  { s = W3;   base = 737280; }
  else if (p < 1474560) { s = W4;   base = 884736; }
  else if (p < 1548288) { s = Wout; base = 1474560; }
  else if (p < 1552896) { s = cw2;  base = 1548288; }
  else return;
  const size_t lp = p - base;
  dst[p] = cvtpk(s[lp * 2], s[lp * 2 + 1]);
}

// ---------------- transpose + bf16 convert: x (4,1536,576) f32 -> xT (4,576,1536) bf16
__global__ __launch_bounds__(256) void k_transpose(const float* __restrict__ x,
                                                   unsigned short* __restrict__ xT) {
  __shared__ float tile[64][65];
  const int t = threadIdx.x;
  const int b = blockIdx.z, c0 = blockIdx.x * 64, p0 = blockIdx.y * 64;
  const int tl = t & 63, th = t >> 6;
#pragma unroll
  for (int r = 0; r < 16; ++r) {
    int c = th * 16 + r;
    tile[c][tl] = x[((size_t)b * 1536 + c0 + c) * 576 + p0 + tl];
  }
  __syncthreads();
#pragma unroll
  for (int r = 0; r < 16; ++r) {
    int p = th * 16 + r;
    xT[((size_t)b * 576 + p0 + p) * 1536 + c0 + tl] = (unsigned short)f2bf1(tile[tl][p]);
  }
}

// ---------------- bf16 MFMA GEMM, 64 x BN tile, BK=64, 3-deep pipeline w/ counted vmcnt
// A: bf16 (4,576,K) k-contig; Wb: bf16 (M,K) k-contig; out: bf16 (4,576,M) or FINAL f32 NCHW+resid
// chunk q -> row = (q>>7)*16 + (q&15); k = ((q>>6)&1)*32 + ((q>>4)&3)*8   (fragment-ordered LDS)
#define ROWOF(q) ((((q) >> 7) << 4) + ((q) & 15))
#define KOF(q)   (((((q) >> 6) & 1) << 5) + ((((q) >> 4) & 3) << 3))
template<int BN, bool BIASADD, bool FINAL>
__global__ __launch_bounds__(256, 4) void k_gemm(const unsigned short* __restrict__ A,
                                                 const unsigned short* __restrict__ Wb,
                                                 const float* __restrict__ bias,
                                                 const float* __restrict__ resid,
                                                 void* __restrict__ outp, int K, int M) {
  constexpr int BCH = BN / 32;  // B staging chunks per thread (2|4); A is always 2
  constexpr int NJT = BN / 32;  // 16-col fragments per wave (wave tile 32 x BN/2)
  __shared__ __align__(16) unsigned short As[3][4096];
  __shared__ __align__(16) unsigned short Bs[3][BN * 64];
  const int t = threadIdx.x;
  const int bz = blockIdx.z, j0 = blockIdx.x * BN, i0 = blockIdx.y * 64;
  const int lane = t & 63, wid = t >> 6;
  const int wi = wid >> 1, wj = wid & 1;
  const int lrow = lane & 15, g4 = lane >> 4;

  const unsigned short* pa0 = A + ((size_t)(bz * 576 + i0 + ROWOF(t))) * K + KOF(t);
  const unsigned short* pa1 = A + ((size_t)(bz * 576 + i0 + ROWOF(t + 256))) * K + KOF(t + 256);
  const unsigned short* pb[BCH];
#pragma unroll
  for (int c = 0; c < BCH; ++c) {
    const int q = t + c * 256;
    pb[c] = Wb + ((size_t)(j0 + ROWOF(q))) * K + KOF(q);
  }
  auto stage = [&](int buf, int ko) {
    gload16(pa0 + ko, &As[buf][t * 8]);
    gload16(pa1 + ko, &As[buf][(t + 256) * 8]);
#pragma unroll
    for (int c = 0; c < BCH; ++c) gload16(pb[c] + ko, &Bs[buf][(t + c * 256) * 8]);
  };
  fx4 acc[2][NJT] = {};
  const int nk = K >> 6;
  stage(0, 0);
  if (nk > 1) stage(1, 64);
  int cur = 0;
  for (int ki = 0; ki < nk; ++ki) {
    // wait: oldest stage (buf=cur) landed; keep next stage(s) in flight across the barrier
    if (ki + 1 < nk) {
      if constexpr (BCH == 2) asm volatile("s_waitcnt vmcnt(4)" ::: "memory");
      else                    asm volatile("s_waitcnt vmcnt(6)" ::: "memory");
    } else {
      asm volatile("s_waitcnt vmcnt(0)" ::: "memory");
    }
    __builtin_amdgcn_s_barrier();
    __builtin_amdgcn_sched_barrier(0);
    asm volatile("" ::: "memory");
    if (ki + 2 < nk) {
      int b2 = cur - 1; if (b2 < 0) b2 = 2;  // (cur+2)%3: the buffer consumed in iter ki-1
      stage(b2, (ki + 2) * 64);
    }
    const unsigned short* ab = &As[cur][0];
    const unsigned short* bb = &Bs[cur][0];
#pragma unroll
    for (int kk = 0; kk < 2; ++kk) {
      bf8 a0 = *(const bf8*)(ab + (((wi * 2 + 0) * 2 + kk) * 64 + lane) * 8);
      bf8 a1 = *(const bf8*)(ab + (((wi * 2 + 1) * 2 + kk) * 64 + lane) * 8);
#pragma unroll
      for (int jt = 0; jt < NJT; ++jt) {
        bf8 b = *(const bf8*)(bb + (((wj * NJT + jt) * 2 + kk) * 64 + lane) * 8);
        acc[0][jt] = __builtin_amdgcn_mfma_f32_16x16x32_bf16(a0, b, acc[0][jt], 0, 0, 0);
        acc[1][jt] = __builtin_amdgcn_mfma_f32_16x16x32_bf16(a1, b, acc[1][jt], 0, 0, 0);
      }
    }
    cur = (cur == 2) ? 0 : cur + 1;
  }
#pragma unroll
  for (int it = 0; it < 2; ++it) {
    const int row0 = i0 + wi * 32 + it * 16 + g4 * 4;
#pragma unroll
    for (int jt = 0; jt < NJT; ++jt) {
      fx4 v = acc[it][jt];
      const int m = j0 + wj * (BN / 2) + jt * 16 + lrow;
      if (BIASADD) {
        float bv = bias[m];
        v[0] += bv; v[1] += bv; v[2] += bv; v[3] += bv;
      }
      if (FINAL) {
        const fx4 xr = *(const fx4*)(resid + ((size_t)bz * M + m) * 576 + row0);
        fx4 ov;
        ov[0] = fmaxf(v[0] + xr[0], 0.f); ov[1] = fmaxf(v[1] + xr[1], 0.f);
        ov[2] = fmaxf(v[2] + xr[2], 0.f); ov[3] = fmaxf(v[3] + xr[3], 0.f);
        *(fx4*)((float*)outp + ((size_t)bz * M + m) * 576 + row0) = ov;
      } else {
        unsigned short* o = (unsigned short*)outp;
#pragma unroll
        for (int r = 0; r < 4; ++r)
          o[((size_t)(bz * 576) + row0 + r) * M + m] = (unsigned short)f2bf1(fmaxf(v[r], 0.f));
      }
    }
  }
}
#undef ROWOF
#undef KOF

// ---------------- grouped 1x1 conv for q
__global__ __launch_bounds__(256) void k_qproj(const unsigned short* __restrict__ h2T,
                                               const float* __restrict__ Wq,
                                               unsigned short* __restrict__ qT) {
  const int idx = blockIdx.x * 256 + threadIdx.x;
  const int c = idx % 384;
  const int n = idx / 384;
  const int g = c / 48, o = c % 48;
  const unsigned short* ap = h2T + (size_t)n * 384 + g * 48;
  const float* wp = Wq + ((size_t)g * 48 + o) * 48;
  float acc = 0.f;
#pragma unroll
  for (int c8 = 0; c8 < 6; ++c8) {
    ux4 u = *(const ux4*)(ap + c8 * 8);
    float va[8]; unp8(u, va);
    fx4 w0 = *(const fx4*)(wp + c8 * 8);
    fx4 w1 = *(const fx4*)(wp + c8 * 8 + 4);
    acc = fmaf(va[0], w0[0], acc); acc = fmaf(va[1], w0[1], acc);
    acc = fmaf(va[2], w0[2], acc); acc = fmaf(va[3], w0[3], acc);
    acc = fmaf(va[4], w1[0], acc); acc = fmaf(va[5], w1[1], acc);
    acc = fmaf(va[6], w1[2], acc); acc = fmaf(va[7], w1[3], acc);
  }
  qT[(size_t)n * 384 + c] = (unsigned short)f2bf1(acc);
}

// ---------------- offsets: depthwise 3x3/s3 -> gelu -> 1x1 (2) -> tanh*4 -> normalized grid
__global__ __launch_bounds__(64, 2) void k_offsets(const unsigned short* __restrict__ qT,
                                                   const float* __restrict__ Wdw,
                                                   const float* __restrict__ bdw,
                                                   const float* __restrict__ Wpw,
                                                   float* __restrict__ vgrid) {
  const int bg = blockIdx.x, t = threadIdx.x;
  const int b = bg >> 3, g = bg & 7;
  const int oy = t >> 3, ox = t & 7;
  float s[48];
#pragma unroll
  for (int ch = 0; ch < 48; ++ch) s[ch] = bdw[ch];
#pragma unroll
  for (int ky = 0; ky < 3; ++ky) {
#pragma unroll
    for (int kx = 0; kx < 3; ++kx) {
      const unsigned short* rp =
          qT + ((size_t)b * 576 + (oy * 3 + ky) * 24 + ox * 3 + kx) * 384 + g * 48;
      const int tap = ky * 3 + kx;
#pragma unroll
      for (int c8 = 0; c8 < 6; ++c8) {
        ux4 u = *(const ux4*)(rp + c8 * 8);
        float va[8]; unp8(u, va);
#pragma unroll
        for (int e = 0; e < 8; ++e)
          s[c8 * 8 + e] = fmaf(va[e], Wdw[(c8 * 8 + e) * 9 + tap], s[c8 * 8 + e]);
      }
    }
  }
  float a0 = 0.f, a1 = 0.f;
#pragma unroll
  for (int ch = 0; ch < 48; ++ch) {
    float z = s[ch];
    float ge = 0.5f * z * (1.f + erff(z * 0.70710678118654752f));
    a0 = fmaf(ge, Wpw[ch], a0);
    a1 = fmaf(ge, Wpw[48 + ch], a1);
  }
  const float off0 = tanhf(a0) * 4.f;
  const float off1 = tanhf(a1) * 4.f;
  vgrid[bg * 128 + t * 2 + 0] = ((float)ox + off0) * (2.f / 7.f) - 1.f;
  vgrid[bg * 128 + t * 2 + 1] = ((float)oy + off1) * (2.f / 7.f) - 1.f;
}

// ---------------- bilinear grid sample (zeros padding, align_corners=False)
__global__ __launch_bounds__(64, 2) void k_gsample(const unsigned short* __restrict__ h2T,
                                                   const float* __restrict__ vgrid,
                                                   unsigned short* __restrict__ kvT) {
  const int bg = blockIdx.x, j = threadIdx.x;
  const int b = bg >> 3, g = bg & 7;
  const float nx = vgrid[bg * 128 + j * 2 + 0];
  const float ny = vgrid[bg * 128 + j * 2 + 1];
  const float xs = ((nx + 1.f) * 24.f - 1.f) * 0.5f;
  const float ys = ((ny + 1.f) * 24.f - 1.f) * 0.5f;
  const float x0f = floorf(xs), y0f = floorf(ys);
  const float wx = xs - x0f, wy = ys - y0f;
  const int x0 = (int)x0f, y0 = (int)y0f;
  float acc[48];
#pragma unroll
  for (int ch = 0; ch < 48; ++ch) acc[ch] = 0.f;
  const float tw[4] = {(1.f - wx) * (1.f - wy), wx * (1.f - wy), (1.f - wx) * wy, wx * wy};
  const int tx[4] = {x0, x0 + 1, x0, x0 + 1};
  const int ty[4] = {y0, y0, y0 + 1, y0 + 1};
#pragma unroll
  for (int tp = 0; tp < 4; ++tp) {
    const int ix = tx[tp], iy = ty[tp];
    const float w = tw[tp] * ((ix >= 0 && ix < 24 && iy >= 0 && iy < 24) ? 1.f : 0.f);
    const int cx = min(max(ix, 0), 23), cy = min(max(iy, 0), 23);
    const unsigned short* rp = h2T + ((size_t)b * 576 + cy * 24 + cx) * 384 + g * 48;
#pragma unroll
    for (int c8 = 0; c8 < 6; ++c8) {
      ux4 u = *(const ux4*)(rp + c8 * 8);
      float va[8]; unp8(u, va);
#pragma unroll
      for (int e = 0; e < 8; ++e) acc[c8 * 8 + e] = fmaf(va[e], w, acc[c8 * 8 + e]);
    }
  }
  unsigned short* op = kvT + ((size_t)bg * 64 + j) * 48;
#pragma unroll
  for (int c2 = 0; c2 < 24; ++c2)
    ((unsigned*)op)[c2] = cvtpk(acc[2 * c2], acc[2 * c2 + 1]);
}

// ---------------- k/v grouped 1x1 conv on kv (f32 out)
__global__ __launch_bounds__(256) void k_kvproj(const unsigned short* __restrict__ kvT,
                                                const float* __restrict__ Wk,
                                                const float* __restrict__ Wv,
                                                float* __restrict__ kT, float* __restrict__ vT) {
  const int bg = blockIdx.x, t = threadIdx.x;
  const int g = bg & 7;
  for (int idx = t; idx < 64 * 48; idx += 256) {
    const int j = idx / 48, o = idx % 48;
    const unsigned short* rp = kvT + ((size_t)bg * 64 + j) * 48;
    const float* wkp = Wk + ((size_t)g * 48 + o) * 48;
    const float* wvp = Wv + ((size_t)g * 48 + o) * 48;
    float ak = 0.f, av = 0.f;
#pragma unroll
    for (int c8 = 0; c8 < 6; ++c8) {
      ux4 u = *(const ux4*)(rp + c8 * 8);
      float va[8]; unp8(u, va);
      fx4 wk0 = *(const fx4*)(wkp + c8 * 8); fx4 wk1 = *(const fx4*)(wkp + c8 * 8 + 4);
      fx4 wv0 = *(const fx4*)(wvp + c8 * 8); fx4 wv1 = *(const fx4*)(wvp + c8 * 8 + 4);
#pragma unroll
      for (int e = 0; e < 4; ++e) {
        ak = fmaf(va[e], wk0[e], ak); ak = fmaf(va[4 + e], wk1[e], ak);
        av = fmaf(va[e], wv0[e], av); av = fmaf(va[4 + e], wv1[e], av);
      }
    }
    kT[(size_t)bg * 3072 + idx] = ak;
    vT[(size_t)bg * 3072 + idx] = av;
  }
}

// ---------------- CPB bias MLP (2 -> 96 -> 96 -> 1), v4: all constants in LDS, 16 i-rows/block
// r6 post-mortem: mt-streaming fixed spills (VGPR 40, 68.7us) but VALU-issue was 2.5x the
// ~10us floor: opaque-offset GLOBAL re-loads of cw1/cb1 (72/thread + 64-bit addressing),
// per-jt global cb2/cw3, per-mt global vgrid, and cw2 staged 4608x for 4 i-rows of work.
// v4: cw1/cb1/cb2/cw3/vgrid-row live in 2.4KB LDS (ds_read w/ opaque LDS int, no addr VALU);
// 4 i-rows per wave (grid /4, staging amortized); cb2 folded into MFMA acc init.
__global__ __launch_bounds__(256) void k_cpb(const float* __restrict__ vgrid,
                                             const float* __restrict__ cw1,
                                             const float* __restrict__ cb1,
                                             const unsigned short* __restrict__ cw2b,
                                             const float* __restrict__ cb2,
                                             const float* __restrict__ cw3,
                                             const float* __restrict__ cb3,
                                             float* __restrict__ pbias) {
  __shared__ __align__(16) unsigned short Ws[1152 * 8];  // 18KB: 18 subtiles (6 jt x 3 kk)
  __shared__ __align__(16) float Cs[608];  // cw1[0:192) cb1[192:288) cb2[288:384) cw3[384:480) vgrid[480:608)
  const int t = threadIdx.x;
  const int bg = blockIdx.y;
  const int wid = t >> 6, lane = t & 63;
  const int lrow = lane & 15, g16 = lane >> 4;
  // stage cw2b -> fragment-ordered LDS
#pragma unroll
  for (int rep = 0; rep < 5; ++rep) {
    const int q = t + rep * 256;
    if (q < 1152) {
      const int s = q >> 6, l = q & 63;
      const int jt = s / 3, kk = s - jt * 3;
      const int n = jt * 16 + (l & 15);
      const int k = kk * 32 + ((l >> 4) & 3) * 8;
      gload16(cw2b + (size_t)n * 96 + k, &Ws[q * 8]);
    }
  }
  // stage small constants + this bg's vgrid row
#pragma unroll
  for (int q = t; q < 480; q += 256) {
    float v;
    if (q < 192) v = cw1[q];
    else if (q < 288) v = cb1[q - 192];
    else if (q < 384) v = cb2[q - 288];
    else v = cw3[q - 384];
    Cs[q] = v;
  }
  if (t < 128) Cs[480 + t] = vgrid[bg * 128 + t];
  const float cb3v = cb3[0];
  __syncthreads();
  // per-lane epilogue constants (12 regs, i/mt-invariant)
  float cb2v[6], cw3v[6];
#pragma unroll
  for (int jt = 0; jt < 6; ++jt) {
    cb2v[jt] = Cs[288 + jt * 16 + lrow];
    cw3v[jt] = Cs[384 + jt * 16 + lrow];
  }
#pragma unroll 1
  for (int il = 0; il < 4; ++il) {
    const int i = blockIdx.x * 16 + wid * 4 + il;
    const float qnx = (float)(i % 24) * (2.f / 23.f) - 1.f;
    const float qny = (float)(i / 24) * (2.f / 23.f) - 1.f;
#pragma unroll 1
    for (int mt = 0; mt < 4; ++mt) {
      // opaque LDS offsets: block LICM from hoisting loop-invariant LDS values into VGPRs
      int c1o = 0, wso = 0;
      asm volatile("" : "+v"(c1o), "+v"(wso));
      const int j = mt * 16 + lrow;
      const fx2 kxy = *(const fx2*)&Cs[c1o + 480 + j * 2];
      const float pu = qnx - kxy[0], pv = qny - kxy[1];
      const float uu = copysignf(__logf(1.f + fabsf(pu)), pu);
      const float vv = copysignf(__logf(1.f + fabsf(pv)), pv);
      bf8 afr[3];
#pragma unroll
      for (int kk = 0; kk < 3; ++kk) {
        const int kb = kk * 32 + g16 * 8;
        fx4 w0 = *(const fx4*)&Cs[c1o + kb * 2];
        fx4 w1 = *(const fx4*)&Cs[c1o + kb * 2 + 4];
        fx4 w2 = *(const fx4*)&Cs[c1o + kb * 2 + 8];
        fx4 w3 = *(const fx4*)&Cs[c1o + kb * 2 + 12];
        fx4 b0 = *(const fx4*)&Cs[c1o + 192 + kb];
        fx4 b1 = *(const fx4*)&Cs[c1o + 192 + kb + 4];
        float h[8];
        h[0] = fmaxf(fmaf(w0[0], uu, fmaf(w0[1], vv, b0[0])), 0.f);
        h[1] = fmaxf(fmaf(w0[2], uu, fmaf(w0[3], vv, b0[1])), 0.f);
        h[2] = fmaxf(fmaf(w1[0], uu, fmaf(w1[1], vv, b0[2])), 0.f);
        h[3] = fmaxf(fmaf(w1[2], uu, fmaf(w1[3], vv, b0[3])), 0.f);
        h[4] = fmaxf(fmaf(w2[0], uu, fmaf(w2[1], vv, b1[0])), 0.f);
        h[5] = fmaxf(fmaf(w2[2], uu, fmaf(w2[3], vv, b1[1])), 0.f);
        h[6] = fmaxf(fmaf(w3[0], uu, fmaf(w3[1], vv, b1[2])), 0.f);
        h[7] = fmaxf(fmaf(w3[2], uu, fmaf(w3[3], vv, b1[3])), 0.f);
        ux4 pk;
        pk[0] = cvtpk(h[0], h[1]); pk[1] = cvtpk(h[2], h[3]);
        pk[2] = cvtpk(h[4], h[5]); pk[3] = cvtpk(h[6], h[7]);
        afr[kk] = *(bf8*)&pk;
      }
      // layer-2 MFMA (acc init = cb2 bias) + fused layer-3 epilogue
      fx4 part = {0.f, 0.f, 0.f, 0.f};
#pragma unroll
      for (int jt = 0; jt < 6; ++jt) {
        bf8 bf0 = *(const bf8*)&Ws[wso + ((jt * 3 + 0) * 64 + lane) * 8];
        bf8 bf1 = *(const bf8*)&Ws[wso + ((jt * 3 + 1) * 64 + lane) * 8];
        bf8 bf2 = *(const bf8*)&Ws[wso + ((jt * 3 + 2) * 64 + lane) * 8];
        fx4 acc = {cb2v[jt], cb2v[jt], cb2v[jt], cb2v[jt]};
        acc = __builtin_amdgcn_mfma_f32_16x16x32_bf16(afr[0], bf0, acc, 0, 0, 0);
        acc = __builtin_amdgcn_mfma_f32_16x16x32_bf16(afr[1], bf1, acc, 0, 0, 0);
        acc = __builtin_amdgcn_mfma_f32_16x16x32_bf16(afr[2], bf2, acc, 0, 0, 0);
#pragma unroll
        for (int r = 0; r < 4; ++r)
          part[r] = fmaf(fmaxf(acc[r], 0.f), cw3v[jt], part[r]);
      }
#pragma unroll
      for (int r = 0; r < 4; ++r) {
        part[r] += __shfl_xor(part[r], 1);
        part[r] += __shfl_xor(part[r], 2);
        part[r] += __shfl_xor(part[r], 4);
        part[r] += __shfl_xor(part[r], 8);
      }
      float pv2 = part[0];
      pv2 = (lrow == 1) ? part[1] : pv2;
      pv2 = (lrow == 2) ? part[2] : pv2;
      pv2 = (lrow == 3) ? part[3] : pv2;
      if (lrow < 4) {
        const int jo = mt * 16 + g16 * 4 + lrow;
        pbias[((size_t)bg * 576 + i) * 64 + jo] = pv2 + cb3v;
      }
    }
  }
}

// ---------------- attention: 4 lanes per query, 16 keys each; shfl-reduce softmax & PV
__global__ __launch_bounds__(256, 3) void k_attn(const unsigned short* __restrict__ qT,
                                                 const float* __restrict__ kT,
                                                 const float* __restrict__ vT,
                                                 const float* __restrict__ pbias,
                                                 unsigned short* __restrict__ aoT) {
  __shared__ __align__(16) float kls[3072];
  __shared__ __align__(16) float vls[3072];
  const int t = threadIdx.x;
  const int ic = blockIdx.x, h = blockIdx.y, b = blockIdx.z;
  const int bg = b * 8 + h;
#pragma unroll
  for (int r = 0; r < 3; ++r) {
    const int idx = t + r * 256;
    ((fx4*)kls)[idx] = ((const fx4*)(kT + (size_t)bg * 3072))[idx];
    ((fx4*)vls)[idx] = ((const fx4*)(vT + (size_t)bg * 3072))[idx];
  }
  __syncthreads();
  const int qi = ic * 64 + (t >> 2);
  const int kg = t & 3;
  const unsigned short* qp = qT + ((size_t)b * 576 + qi) * 384 + h * 48;
  const float scale = 0.14433756729740643f;  // 48^-0.5
  float q[48];
#pragma unroll
  for (int c8 = 0; c8 < 6; ++c8) {
    ux4 u = *(const ux4*)(qp + c8 * 8);
    float va[8]; unp8(u, va);
#pragma unroll
    for (int e = 0; e < 8; ++e) q[c8 * 8 + e] = va[e] * scale;
  }
  float s[16];
  const float* kbase = kls + kg * 16 * 48;
#pragma unroll
  for (int it = 0; it < 16; ++it) {
    const fx4* kr = (const fx4*)(kbase + it * 48);
    float a0 = 0.f, a1 = 0.f;
#pragma unroll
    for (int d4 = 0; d4 < 6; ++d4) {
      fx4 k0 = kr[2 * d4], k1 = kr[2 * d4 + 1];
      a0 = fmaf(q[8 * d4 + 0], k0[0], a0); a0 = fmaf(q[8 * d4 + 1], k0[1], a0);
      a0 = fmaf(q[8 * d4 + 2], k0[2], a0); a0 = fmaf(q[8 * d4 + 3], k0[3], a0);
      a1 = fmaf(q[8 * d4 + 4], k1[0], a1); a1 = fmaf(q[8 * d4 + 5], k1[1], a1);
      a1 = fmaf(q[8 * d4 + 6], k1[2], a1); a1 = fmaf(q[8 * d4 + 7], k1[3], a1);
    }
    s[it] = a0 + a1;
  }
  const float* bp = pbias + ((size_t)bg * 576 + qi) * 64 + kg * 16;
#pragma unroll
  for (int i4 = 0; i4 < 4; ++i4) {
    fx4 bv = ((const fx4*)bp)[i4];
    s[i4 * 4 + 0] += bv[0]; s[i4 * 4 + 1] += bv[1];
    s[i4 * 4 + 2] += bv[2]; s[i4 * 4 + 3] += bv[3];
  }
  float mx = s[0];
#pragma unroll
  for (int it = 1; it < 16; ++it) mx = fmaxf(mx, s[it]);
  mx = fmaxf(mx, __shfl_xor(mx, 1));
  mx = fmaxf(mx, __shfl_xor(mx, 2));
  float sum = 0.f;
#pragma unroll
  for (int it = 0; it < 16; ++it) { s[it] = __expf(s[it] - mx); sum += s[it]; }
  sum += __shfl_xor(sum, 1);
  sum += __shfl_xor(sum, 2);
  const float inv = 1.f / sum;
#pragma unroll
  for (int it = 0; it < 16; ++it) s[it] *= inv;
  float acc[48];
#pragma unroll
  for (int d = 0; d < 48; ++d) acc[d] = 0.f;
  const float* vbase = vls + kg * 16 * 48;
#pragma unroll
  for (int it = 0; it < 16; ++it) {
    const float p = s[it];
    const fx4* vr = (const fx4*)(vbase + it * 48);
#pragma unroll
    for (int d4 = 0; d4 < 12; ++d4) {
      fx4 v = vr[d4];
      acc[d4 * 4 + 0] = fmaf(p, v[0], acc[d4 * 4 + 0]);
      acc[d4 * 4 + 1] = fmaf(p, v[1], acc[d4 * 4 + 1]);
      acc[d4 * 4 + 2] = fmaf(p, v[2], acc[d4 * 4 + 2]);
      acc[d4 * 4 + 3] = fmaf(p, v[3], acc[d4 * 4 + 3]);
    }
  }
#pragma unroll
  for (int d = 0; d < 48; ++d) {
    acc[d] += __shfl_xor(acc[d], 1);
    acc[d] += __shfl_xor(acc[d], 2);
  }
  unsigned* op32 = (unsigned*)(aoT + ((size_t)b * 576 + qi) * 384 + h * 48);
  if (kg == 0) {
#pragma unroll
    for (int p2 = 0; p2 < 6; ++p2) op32[p2] = cvtpk(acc[p2 * 2], acc[p2 * 2 + 1]);
  } else if (kg == 1) {
#pragma unroll
    for (int p2 = 0; p2 < 6; ++p2) op32[6 + p2] = cvtpk(acc[12 + p2 * 2], acc[13 + p2 * 2]);
  } else if (kg == 2) {
#pragma unroll
    for (int p2 = 0; p2 < 6; ++p2) op32[12 + p2] = cvtpk(acc[24 + p2 * 2], acc[25 + p2 * 2]);
  } else {
#pragma unroll
    for (int p2 = 0; p2 < 6; ++p2) op32[18 + p2] = cvtpk(acc[36 + p2 * 2], acc[37 + p2 * 2]);
  }
}

extern "C" void kernel_launch(void* const* d_in, const int* in_sizes, int n_in,
                              void* d_out, int out_size, void* d_ws, size_t ws_size,
                              hipStream_t stream) {
  (void)in_sizes; (void)n_in; (void)out_size; (void)ws_size;
  const float* x    = (const float*)d_in[0];
  const float* W1   = (const float*)d_in[1];
  const float* W2   = (const float*)d_in[2];
  const float* W3   = (const float*)d_in[3];
  const float* W4   = (const float*)d_in[4];
  const float* Wq   = (const float*)d_in[5];
  const float* Wk   = (const float*)d_in[6];
  const float* Wv   = (const float*)d_in[7];
  const float* Wdw  = (const float*)d_in[8];
  const float* bdw  = (const float*)d_in[9];
  const float* Wpw  = (const float*)d_in[10];
  const float* cw1  = (const float*)d_in[11];
  const float* cb1  = (const float*)d_in[12];
  const float* cw2  = (const float*)d_in[13];
  const float* cb2  = (const float*)d_in[14];
  const float* cw3  = (const float*)d_in[15];
  const float* cb3  = (const float*)d_in[16];
  const float* Wout = (const float*)d_in[17];
  const float* bout = (const float*)d_in[18];

  char* ws = (char*)d_ws;
  size_t off = 0;
  auto alloc = [&](size_t bytes) {
    void* p = ws + off;
    off += (bytes + 255) & ~(size_t)255;
    return p;
  };
  unsigned short* xT  = (unsigned short*)alloc((size_t)4 * 576 * 1536 * 2);
  unsigned short* h1T = (unsigned short*)alloc((size_t)4 * 576 * 768 * 2);
  unsigned short* h2T = (unsigned short*)alloc((size_t)4 * 576 * 384 * 2);
  unsigned short* qT  = (unsigned short*)alloc((size_t)4 * 576 * 384 * 2);
  unsigned short* aoT = (unsigned short*)alloc((size_t)4 * 576 * 384 * 2);
  unsigned short* AT  = (unsigned short*)alloc((size_t)4 * 576 * 384 * 2);
  unsigned short* h3T = (unsigned short*)alloc((size_t)4 * 576 * 768 * 2);
  float* vgrid = (float*)alloc((size_t)32 * 64 * 2 * 4);
  unsigned short* kvT = (unsigned short*)alloc((size_t)32 * 64 * 48 * 2);
  float* kTb  = (float*)alloc((size_t)32 * 64 * 48 * 4);
  float* vTb  = (float*)alloc((size_t)32 * 64 * 48 * 4);
  float* pbias = (float*)alloc((size_t)32 * 576 * 64 * 4);
  unsigned short* Wcvt = (unsigned short*)alloc((size_t)3105792 * 2);  // bf16 weights
  const unsigned short* W1b   = Wcvt;
  const unsigned short* W2b   = Wcvt + 1179648;
  const unsigned short* W3b   = Wcvt + 1474560;
  const unsigned short* W4b   = Wcvt + 1769472;
  const unsigned short* Woutb = Wcvt + 2949120;
  const unsigned short* cw2b  = Wcvt + 3096576;

  k_wconv<<<6066, 256, 0, stream>>>(W1, W2, W3, W4, Wout, cw2, (unsigned*)Wcvt);
  k_transpose<<<dim3(24, 9, 4), 256, 0, stream>>>(x, xT);
  k_gemm<64, false, false><<<dim3(12, 9, 4), 256, 0, stream>>>(xT, W1b, nullptr, nullptr, h1T, 1536, 768);
  k_gemm<64, false, false><<<dim3(6, 9, 4), 256, 0, stream>>>(h1T, W2b, nullptr, nullptr, h2T, 768, 384);
  k_qproj<<<3456, 256, 0, stream>>>(h2T, Wq, qT);
  k_offsets<<<32, 64, 0, stream>>>(qT, Wdw, bdw, Wpw, vgrid);
  k_gsample<<<32, 64, 0, stream>>>(h2T, vgrid, kvT);
  k_kvproj<<<32, 256, 0, stream>>>(kvT, Wk, Wv, kTb, vTb);
  k_cpb<<<dim3(36, 32), 256, 0, stream>>>(vgrid, cw1, cb1, cw2b, cb2, cw3, cb3, pbias);
  k_attn<<<dim3(9, 8, 4), 256, 0, stream>>>(qT, kTb, vTb, pbias, aoT);
  k_gemm<64, true, false><<<dim3(6, 9, 4), 256, 0, stream>>>(aoT, Woutb, bout, nullptr, AT, 384, 384);
  k_gemm<64, false, false><<<dim3(12, 9, 4), 256, 0, stream>>>(AT, W3b, nullptr, nullptr, h3T, 384, 768);
  k_gemm<128, false, true><<<dim3(12, 9, 4), 256, 0, stream>>>(h3T, W4b, nullptr, x, d_out, 768, 1536);
}